// Round 1
// baseline (1516.820 us; speedup 1.0000x reference)
//
#include <hip/hip_runtime.h>
#include <hip/hip_bf16.h>

#define NEG_SLOPE 0.2f

__device__ __forceinline__ float lrelu(float x){ return x > 0.f ? x : NEG_SLOPE * x; }
__device__ __forceinline__ float elu1(float x){ return x > 0.f ? x : expm1f(x); }
// float -> ordered uint encoding for atomicMax over signed floats
__device__ __forceinline__ unsigned fenc(float f){
  unsigned u = __float_as_uint(f);
  return (u & 0x80000000u) ? ~u : (u | 0x80000000u);
}
__device__ __forceinline__ float fdec(unsigned u){
  return (u & 0x80000000u) ? __uint_as_float(u & 0x7fffffffu) : __uint_as_float(~u);
}

__global__ void k_init(unsigned* m1u, float* den1, unsigned* m2u, float* den2,
                       float* acc2, int* cnt, int N){
  int i = blockIdx.x * blockDim.x + threadIdx.x;
  if (i < N * 4){ m1u[i] = 0u; den1[i] = 0.f; }
  if (i < N){ m2u[i] = 0u; den2[i] = 0.f; acc2[i] = 0.f; cnt[i] = 1; } // cnt=1 for self-loop
}

// h1 = x @ W1 ; a_s[n,h] = <h1[n,h,:], att_src[h,:]> ; a_d likewise.
// One row per block, 128 threads (one output channel each).
__global__ void k_gemm1(const float* __restrict__ x, const float* __restrict__ W1,
                        const float* __restrict__ atts, const float* __restrict__ attd,
                        float* __restrict__ h1, float* __restrict__ as1, float* __restrict__ ad1,
                        int N){
  int n = blockIdx.x;
  int j = threadIdx.x;
  __shared__ float xr[128];
  xr[j] = x[(size_t)n * 128 + j];
  __syncthreads();
  float acc = 0.f;
  #pragma unroll
  for (int k = 0; k < 128; ++k) acc = fmaf(xr[k], W1[k * 128 + j], acc);
  h1[(size_t)n * 128 + j] = acc;
  float s = acc * atts[j];
  float d = acc * attd[j];
  #pragma unroll
  for (int off = 16; off; off >>= 1){
    s += __shfl_down(s, off, 32);
    d += __shfl_down(d, off, 32);
  }
  if ((j & 31) == 0){
    int h = j >> 5;
    as1[n * 4 + h] = s;
    ad1[n * 4 + h] = d;
  }
}

__global__ void k_hist(const int* __restrict__ ei, int* __restrict__ cnt, int E){
  int i = blockIdx.x * blockDim.x + threadIdx.x;
  if (i < E) atomicAdd(&cnt[ei[E + i]], 1);
}

// single-workgroup exclusive scan over cnt[0..n) -> row_start, cursor
__global__ void k_scan(const int* __restrict__ cnt, int* __restrict__ rs,
                       int* __restrict__ cursor, int n){
  __shared__ int buf[256];
  __shared__ int carry_s;
  if (threadIdx.x == 0) carry_s = 0;
  __syncthreads();
  for (int base = 0; base < n; base += 256){
    int i = base + (int)threadIdx.x;
    int v = (i < n) ? cnt[i] : 0;
    buf[threadIdx.x] = v;
    __syncthreads();
    #pragma unroll
    for (int off = 1; off < 256; off <<= 1){
      int t = (threadIdx.x >= (unsigned)off) ? buf[threadIdx.x - off] : 0;
      __syncthreads();
      buf[threadIdx.x] += t;
      __syncthreads();
    }
    int incl = buf[threadIdx.x];
    int carry = carry_s;
    if (i < n){ int excl = carry + incl - v; rs[i] = excl; cursor[i] = excl; }
    __syncthreads();                    // everyone read carry_s
    if (threadIdx.x == 255) carry_s = carry + buf[255];
    __syncthreads();
  }
  if (threadIdx.x == 0) rs[n] = carry_s;
}

__global__ void k_scatter(const int* __restrict__ ei, int* __restrict__ cursor,
                          int* __restrict__ csr, int E, int N){
  int i = blockIdx.x * blockDim.x + threadIdx.x;
  int T = E + N;
  if (i >= T) return;
  int s, d;
  if (i < E){ s = ei[i]; d = ei[E + i]; } else { s = d = i - E; }
  int pos = atomicAdd(&cursor[d], 1);
  csr[pos] = s;
}

__global__ void k_edgemax1(const int* __restrict__ ei, const float4* __restrict__ as1,
                           const float4* __restrict__ ad1, unsigned* __restrict__ m1u,
                           int E, int N){
  int i = blockIdx.x * blockDim.x + threadIdx.x;
  int T = E + N;
  if (i >= T) return;
  int s, d;
  if (i < E){ s = ei[i]; d = ei[E + i]; } else { s = d = i - E; }
  float4 a = as1[s], b = ad1[d];
  atomicMax(&m1u[d * 4 + 0], fenc(lrelu(a.x + b.x)));
  atomicMax(&m1u[d * 4 + 1], fenc(lrelu(a.y + b.y)));
  atomicMax(&m1u[d * 4 + 2], fenc(lrelu(a.z + b.z)));
  atomicMax(&m1u[d * 4 + 3], fenc(lrelu(a.w + b.w)));
}

__global__ void k_edgeden1(const int* __restrict__ ei, const float4* __restrict__ as1,
                           const float4* __restrict__ ad1, const unsigned* __restrict__ m1u,
                           float* __restrict__ den1, int E, int N){
  int i = blockIdx.x * blockDim.x + threadIdx.x;
  int T = E + N;
  if (i >= T) return;
  int s, d;
  if (i < E){ s = ei[i]; d = ei[E + i]; } else { s = d = i - E; }
  float4 a = as1[s], b = ad1[d];
  atomicAdd(&den1[d * 4 + 0], expf(lrelu(a.x + b.x) - fdec(m1u[d * 4 + 0])));
  atomicAdd(&den1[d * 4 + 1], expf(lrelu(a.y + b.y) - fdec(m1u[d * 4 + 1])));
  atomicAdd(&den1[d * 4 + 2], expf(lrelu(a.z + b.z) - fdec(m1u[d * 4 + 2])));
  atomicAdd(&den1[d * 4 + 3], expf(lrelu(a.w + b.w) - fdec(m1u[d * 4 + 3])));
}

// One wave per destination node. Lane l owns channels 2l,2l+1.
// Fuses: softmax-weighted gather, /denom, +bias, ELU, dot with W2 -> h2[d].
__global__ void k_agg1(const int* __restrict__ csr, const int* __restrict__ rs,
                       const float* __restrict__ as1, const float* __restrict__ ad1,
                       const unsigned* __restrict__ m1u, const float* __restrict__ den1,
                       const float2* __restrict__ h1, const float* __restrict__ bias1,
                       const float* __restrict__ W2, float* __restrict__ h2, int N){
  int wv = threadIdx.x >> 6;
  int lane = threadIdx.x & 63;
  int d = blockIdx.x * 4 + wv;
  if (d >= N) return;
  int h = lane >> 4;                     // head of channel 2*lane
  float adh = ad1[d * 4 + h];
  float mh = fdec(m1u[d * 4 + h]);
  float invden = 1.f / den1[d * 4 + h];
  int beg = rs[d], end = rs[d + 1];
  float ax = 0.f, ay = 0.f;
  for (int j = beg; j < end; ++j){
    int s = csr[j];
    float e = lrelu(as1[s * 4 + h] + adh);
    float p = expf(e - mh);
    float2 hv = h1[(size_t)s * 64 + lane];
    ax = fmaf(p, hv.x, ax);
    ay = fmaf(p, hv.y, ay);
  }
  float ox = elu1(ax * invden + bias1[2 * lane]);
  float oy = elu1(ay * invden + bias1[2 * lane + 1]);
  float part = fmaf(ox, W2[2 * lane], oy * W2[2 * lane + 1]);
  #pragma unroll
  for (int off = 32; off; off >>= 1) part += __shfl_down(part, off);
  if (lane == 0) h2[d] = part;
}

__global__ void k_edgemax2(const int* __restrict__ ei, const float* __restrict__ h2,
                           const float* __restrict__ as2p, const float* __restrict__ ad2p,
                           unsigned* __restrict__ m2u, int E, int N){
  int i = blockIdx.x * blockDim.x + threadIdx.x;
  int T = E + N;
  if (i >= T) return;
  int s, d;
  if (i < E){ s = ei[i]; d = ei[E + i]; } else { s = d = i - E; }
  float e = lrelu(h2[s] * as2p[0] + h2[d] * ad2p[0]);
  atomicMax(&m2u[d], fenc(e));
}

__global__ void k_edge2(const int* __restrict__ ei, const float* __restrict__ h2,
                        const float* __restrict__ as2p, const float* __restrict__ ad2p,
                        const unsigned* __restrict__ m2u, float* __restrict__ den2,
                        float* __restrict__ acc2, int E, int N){
  int i = blockIdx.x * blockDim.x + threadIdx.x;
  int T = E + N;
  if (i >= T) return;
  int s, d;
  if (i < E){ s = ei[i]; d = ei[E + i]; } else { s = d = i - E; }
  float hs = h2[s];
  float e = lrelu(hs * as2p[0] + h2[d] * ad2p[0]);
  float p = expf(e - fdec(m2u[d]));
  atomicAdd(&den2[d], p);
  atomicAdd(&acc2[d], p * hs);
}

__global__ void k_final(const float* __restrict__ acc2, const float* __restrict__ den2,
                        const float* __restrict__ bias2, float* __restrict__ out, int N){
  int i = blockIdx.x * blockDim.x + threadIdx.x;
  if (i < N) out[i] = acc2[i] / den2[i] + bias2[0];
}

extern "C" void kernel_launch(void* const* d_in, const int* in_sizes, int n_in,
                              void* d_out, int out_size, void* d_ws, size_t ws_size,
                              hipStream_t stream){
  const float* x     = (const float*)d_in[0];
  const int*   ei    = (const int*)  d_in[1];
  const float* W1    = (const float*)d_in[2];
  const float* atts1 = (const float*)d_in[3];
  const float* attd1 = (const float*)d_in[4];
  const float* bias1 = (const float*)d_in[5];
  const float* W2    = (const float*)d_in[6];
  const float* atts2 = (const float*)d_in[7];
  const float* attd2 = (const float*)d_in[8];
  const float* bias2 = (const float*)d_in[9];

  int N = in_sizes[0] / 128;   // D = 128
  int E = in_sizes[1] / 2;

  // workspace layout (fp32 units)
  float*    h1   = (float*)d_ws;                       // N*128
  float*    as1  = h1  + (size_t)N * 128;              // N*4
  float*    ad1  = as1 + (size_t)N * 4;                // N*4
  unsigned* m1u  = (unsigned*)(ad1 + (size_t)N * 4);   // N*4
  float*    den1 = (float*)(m1u + (size_t)N * 4);      // N*4
  float*    h2   = den1 + (size_t)N * 4;               // N
  unsigned* m2u  = (unsigned*)(h2 + N);                // N
  float*    den2 = (float*)(m2u + N);                  // N
  float*    acc2 = den2 + N;                           // N
  int*      cnt  = (int*)(acc2 + N);                   // N
  int*      rs   = cnt + N;                            // N+1
  int*      cursor = rs + N + 1;                       // N
  int*      csr  = cursor + N;                         // E+N

  int T = E + N;
  k_init    <<<(N * 4 + 255) / 256, 256, 0, stream>>>(m1u, den1, m2u, den2, acc2, cnt, N);
  k_gemm1   <<<N, 128, 0, stream>>>(x, W1, atts1, attd1, h1, as1, ad1, N);
  k_hist    <<<(E + 255) / 256, 256, 0, stream>>>(ei, cnt, E);
  k_scan    <<<1, 256, 0, stream>>>(cnt, rs, cursor, N);
  k_scatter <<<(T + 255) / 256, 256, 0, stream>>>(ei, cursor, csr, E, N);
  k_edgemax1<<<(T + 255) / 256, 256, 0, stream>>>(ei, (const float4*)as1, (const float4*)ad1, m1u, E, N);
  k_edgeden1<<<(T + 255) / 256, 256, 0, stream>>>(ei, (const float4*)as1, (const float4*)ad1, m1u, den1, E, N);
  k_agg1    <<<(N + 3) / 4, 256, 0, stream>>>(csr, rs, as1, ad1, m1u, den1, (const float2*)h1, bias1, W2, h2, N);
  k_edgemax2<<<(T + 255) / 256, 256, 0, stream>>>(ei, h2, atts2, attd2, m2u, E, N);
  k_edge2   <<<(T + 255) / 256, 256, 0, stream>>>(ei, h2, atts2, attd2, m2u, den2, acc2, E, N);
  k_final   <<<(N + 255) / 256, 256, 0, stream>>>(acc2, den2, bias2, (float*)d_out, N);
}

// Round 2
// 626.525 us; speedup vs baseline: 2.4210x; 2.4210x over previous
//
#include <hip/hip_runtime.h>
#include <hip/hip_bf16.h>

#define NEG_SLOPE 0.2f

__device__ __forceinline__ float lrelu(float x){ return x > 0.f ? x : NEG_SLOPE * x; }
__device__ __forceinline__ float elu1(float x){ return x > 0.f ? x : expm1f(x); }

__global__ void k_init(int* cnt, int N){
  int i = blockIdx.x * blockDim.x + threadIdx.x;
  if (i < N) cnt[i] = 1;   // self-loop
}

// h1 = x @ W1 ; a_s[n,h] = <h1[n,h,:], att_src[h,:]> ; a_d likewise.
// One row per block, 128 threads (one output channel each).
__global__ void k_gemm1(const float* __restrict__ x, const float* __restrict__ W1,
                        const float* __restrict__ atts, const float* __restrict__ attd,
                        float* __restrict__ h1, float* __restrict__ as1, float* __restrict__ ad1,
                        int N){
  int n = blockIdx.x;
  int j = threadIdx.x;
  __shared__ float xr[128];
  xr[j] = x[(size_t)n * 128 + j];
  __syncthreads();
  float acc = 0.f;
  #pragma unroll
  for (int k = 0; k < 128; ++k) acc = fmaf(xr[k], W1[k * 128 + j], acc);
  h1[(size_t)n * 128 + j] = acc;
  float s = acc * atts[j];
  float d = acc * attd[j];
  #pragma unroll
  for (int off = 16; off; off >>= 1){
    s += __shfl_down(s, off, 32);
    d += __shfl_down(d, off, 32);
  }
  if ((j & 31) == 0){
    int h = j >> 5;
    as1[n * 4 + h] = s;
    ad1[n * 4 + h] = d;
  }
}

__global__ void k_hist(const int* __restrict__ ei, int* __restrict__ cnt, int E){
  int i = blockIdx.x * blockDim.x + threadIdx.x;
  if (i < E) atomicAdd(&cnt[ei[E + i]], 1);
}

// single-workgroup exclusive scan (1024 threads, shfl-based) -> row_start, cursor
__global__ void k_scan(const int* __restrict__ cnt, int* __restrict__ rs,
                       int* __restrict__ cursor, int n){
  __shared__ int wsum[16];
  __shared__ int carry_s;
  int lane = threadIdx.x & 63, wid = threadIdx.x >> 6;
  if (threadIdx.x == 0) carry_s = 0;
  __syncthreads();
  for (int base = 0; base < n; base += 1024){
    int i = base + (int)threadIdx.x;
    int v = (i < n) ? cnt[i] : 0;
    int x = v;
    #pragma unroll
    for (int off = 1; off < 64; off <<= 1){
      int t = __shfl_up(x, off, 64);
      if (lane >= off) x += t;
    }
    if (lane == 63) wsum[wid] = x;
    __syncthreads();
    if (wid == 0 && lane < 16){
      int w = wsum[lane];
      #pragma unroll
      for (int off = 1; off < 16; off <<= 1){
        int t = __shfl_up(w, off, 64);
        if (lane >= off) w += t;
      }
      wsum[lane] = w;
    }
    __syncthreads();
    int carry = carry_s;
    int prefix = carry + (wid ? wsum[wid - 1] : 0);
    if (i < n){ int excl = prefix + x - v; rs[i] = excl; cursor[i] = excl; }
    __syncthreads();
    if (threadIdx.x == 1023) carry_s = carry + wsum[15];
    __syncthreads();
  }
  if (threadIdx.x == 0) rs[n] = carry_s;
}

__global__ void k_scatter(const int* __restrict__ ei, int* __restrict__ cursor,
                          int* __restrict__ csr, int E, int N){
  int i = blockIdx.x * blockDim.x + threadIdx.x;
  int T = E + N;
  if (i >= T) return;
  int s, d;
  if (i < E){ s = ei[i]; d = ei[E + i]; } else { s = d = i - E; }
  int pos = atomicAdd(&cursor[d], 1);
  csr[pos] = s;
}

// One wave per destination node. Lane l owns channels 2l,2l+1 (head h = l>>4).
// Pass 1: per-head segment max (registers only). Pass 2: softmax-weighted
// gather of h1, /denom, +bias, ELU, dot with W2 -> h2[d]. Zero atomics.
__global__ void k_agg1(const int* __restrict__ csr, const int* __restrict__ rs,
                       const float* __restrict__ as1, const float* __restrict__ ad1,
                       const float2* __restrict__ h1, const float* __restrict__ bias1,
                       const float* __restrict__ W2, float* __restrict__ h2, int N){
  int wv = threadIdx.x >> 6;
  int lane = threadIdx.x & 63;
  int d = blockIdx.x * 4 + wv;
  if (d >= N) return;
  int h = lane >> 4;                     // head of channel 2*lane
  float adh = ad1[d * 4 + h];
  int beg = rs[d], end = rs[d + 1];
  // pass 1: max over incoming edges (lanes in a 16-group compute identical m)
  float m = -INFINITY;
  for (int j = beg; j < end; ++j){
    int s = csr[j];
    m = fmaxf(m, lrelu(as1[s * 4 + h] + adh));
  }
  // pass 2: weighted gather
  float den = 0.f, ax = 0.f, ay = 0.f;
  for (int j = beg; j < end; ++j){
    int s = csr[j];
    float e = lrelu(as1[s * 4 + h] + adh);
    float p = expf(e - m);
    den += p;
    float2 hv = h1[(size_t)s * 64 + lane];
    ax = fmaf(p, hv.x, ax);
    ay = fmaf(p, hv.y, ay);
  }
  float invden = 1.f / den;
  float ox = elu1(ax * invden + bias1[2 * lane]);
  float oy = elu1(ay * invden + bias1[2 * lane + 1]);
  float part = fmaf(ox, W2[2 * lane], oy * W2[2 * lane + 1]);
  #pragma unroll
  for (int off = 32; off; off >>= 1) part += __shfl_down(part, off);
  if (lane == 0) h2[d] = part;
}

// Layer 2: one wave per destination, lanes strided over its edge list.
// h2 is [N] floats (200 KB, L2-resident). Writes final output.
__global__ void k_agg2(const int* __restrict__ csr, const int* __restrict__ rs,
                       const float* __restrict__ h2,
                       const float* __restrict__ as2p, const float* __restrict__ ad2p,
                       const float* __restrict__ bias2, float* __restrict__ out, int N){
  int wv = threadIdx.x >> 6;
  int lane = threadIdx.x & 63;
  int d = blockIdx.x * 4 + wv;
  if (d >= N) return;
  float asc = as2p[0];
  float hd = h2[d] * ad2p[0];
  int beg = rs[d], end = rs[d + 1];
  float m = -INFINITY;
  for (int j = beg + lane; j < end; j += 64){
    float e = lrelu(h2[csr[j]] * asc + hd);
    m = fmaxf(m, e);
  }
  #pragma unroll
  for (int off = 32; off; off >>= 1) m = fmaxf(m, __shfl_xor(m, off));
  float den = 0.f, acc = 0.f;
  for (int j = beg + lane; j < end; j += 64){
    float hs = h2[csr[j]];
    float e = lrelu(hs * asc + hd);
    float p = expf(e - m);
    den += p;
    acc = fmaf(p, hs, acc);
  }
  #pragma unroll
  for (int off = 32; off; off >>= 1){
    den += __shfl_xor(den, off);
    acc += __shfl_xor(acc, off);
  }
  if (lane == 0) out[d] = acc / den + bias2[0];
}

extern "C" void kernel_launch(void* const* d_in, const int* in_sizes, int n_in,
                              void* d_out, int out_size, void* d_ws, size_t ws_size,
                              hipStream_t stream){
  const float* x     = (const float*)d_in[0];
  const int*   ei    = (const int*)  d_in[1];
  const float* W1    = (const float*)d_in[2];
  const float* atts1 = (const float*)d_in[3];
  const float* attd1 = (const float*)d_in[4];
  const float* bias1 = (const float*)d_in[5];
  const float* W2    = (const float*)d_in[6];
  const float* atts2 = (const float*)d_in[7];
  const float* attd2 = (const float*)d_in[8];
  const float* bias2 = (const float*)d_in[9];

  int N = in_sizes[0] / 128;   // D = 128
  int E = in_sizes[1] / 2;

  // workspace layout (fp32 units)
  float*    h1   = (float*)d_ws;                       // N*128
  float*    as1  = h1  + (size_t)N * 128;              // N*4
  float*    ad1  = as1 + (size_t)N * 4;                // N*4
  float*    h2   = ad1 + (size_t)N * 4;                // N
  int*      cnt  = (int*)(h2 + N);                     // N
  int*      rs   = cnt + N;                            // N+1
  int*      cursor = rs + N + 1;                       // N
  int*      csr  = cursor + N;                         // E+N

  int T = E + N;
  k_init    <<<(N + 255) / 256, 256, 0, stream>>>(cnt, N);
  k_gemm1   <<<N, 128, 0, stream>>>(x, W1, atts1, attd1, h1, as1, ad1, N);
  k_hist    <<<(E + 255) / 256, 256, 0, stream>>>(ei, cnt, E);
  k_scan    <<<1, 1024, 0, stream>>>(cnt, rs, cursor, N);
  k_scatter <<<(T + 255) / 256, 256, 0, stream>>>(ei, cursor, csr, E, N);
  k_agg1    <<<(N + 3) / 4, 256, 0, stream>>>(csr, rs, as1, ad1, (const float2*)h1, bias1, W2, h2, N);
  k_agg2    <<<(N + 3) / 4, 256, 0, stream>>>(csr, rs, h2, atts2, attd2, bias2, (float*)d_out, N);
}

// Round 3
// 485.128 us; speedup vs baseline: 3.1266x; 1.2915x over previous
//
#include <hip/hip_runtime.h>
#include <hip/hip_bf16.h>

#define NEG_SLOPE 0.2f

__device__ __forceinline__ float lrelu(float x){ return x > 0.f ? x : NEG_SLOPE * x; }
__device__ __forceinline__ float elu1(float x){ return x > 0.f ? x : expm1f(x); }
// float -> ordered uint encoding for atomicMax over signed floats
__device__ __forceinline__ unsigned fenc(float f){
  unsigned u = __float_as_uint(f);
  return (u & 0x80000000u) ? ~u : (u | 0x80000000u);
}
__device__ __forceinline__ float fdec(unsigned u){
  return (u & 0x80000000u) ? __uint_as_float(u & 0x7fffffffu) : __uint_as_float(~u);
}

__global__ void k_init(int* cnt, unsigned* asmaxu, int N){
  int i = blockIdx.x * blockDim.x + threadIdx.x;
  if (i < N) cnt[i] = 1;   // self-loop
  if (i < 4) asmaxu[i] = 0u;
}

// h1 = x @ W1 (N x 128 @ 128 x 128), fused a_s/a_d row dots.
// Block: 256 threads = 8 rows; thread t -> row (t>>5), cols 4*(t&31)..+3.
__global__ void k_gemm1(const float* __restrict__ x, const float* __restrict__ W1,
                        const float* __restrict__ atts, const float* __restrict__ attd,
                        float* __restrict__ h1, float* __restrict__ as1, float* __restrict__ ad1,
                        int N){
  __shared__ float xs[8][128];
  int n0 = blockIdx.x * 8;
  int t = threadIdx.x;
  #pragma unroll
  for (int i = 0; i < 4; ++i){
    int idx = t + i * 256;
    int r = idx >> 7, c = idx & 127;
    int n = n0 + r;
    xs[r][c] = (n < N) ? x[(size_t)n * 128 + c] : 0.f;
  }
  __syncthreads();
  int m = t & 31, r = t >> 5;
  const float4* W14 = (const float4*)W1;
  float a0 = 0.f, a1 = 0.f, a2 = 0.f, a3 = 0.f;
  #pragma unroll 4
  for (int k = 0; k < 128; ++k){
    float4 w = W14[k * 32 + m];
    float xv = xs[r][k];
    a0 = fmaf(xv, w.x, a0);
    a1 = fmaf(xv, w.y, a1);
    a2 = fmaf(xv, w.z, a2);
    a3 = fmaf(xv, w.w, a3);
  }
  int n = n0 + r;
  if (n < N) ((float4*)h1)[(size_t)n * 32 + m] = make_float4(a0, a1, a2, a3);
  // fused a_s/a_d: channels 4m..4m+3 all in head (m>>3)
  float4 av = ((const float4*)atts)[m];
  float4 dv = ((const float4*)attd)[m];
  float s  = a0 * av.x + a1 * av.y + a2 * av.z + a3 * av.w;
  float dd = a0 * dv.x + a1 * dv.y + a2 * dv.z + a3 * dv.w;
  #pragma unroll
  for (int off = 4; off; off >>= 1){
    s  += __shfl_down(s, off);
    dd += __shfl_down(dd, off);
  }
  if ((m & 7) == 0 && n < N){
    as1[n * 4 + (m >> 3)] = s;
    ad1[n * 4 + (m >> 3)] = dd;
  }
}

// global per-head max of a_s (upper bound input for softmax stabilization)
__global__ void k_asmax(const float* __restrict__ as1, unsigned* __restrict__ asmaxu, int N4){
  float mx = -INFINITY;
  for (int i = blockIdx.x * blockDim.x + threadIdx.x; i < N4; i += gridDim.x * blockDim.x)
    mx = fmaxf(mx, as1[i]);
  #pragma unroll
  for (int off = 4; off < 64; off <<= 1) mx = fmaxf(mx, __shfl_xor(mx, off));
  int lane = threadIdx.x & 63;
  if (lane < 4) atomicMax(&asmaxu[(threadIdx.x & 3)], fenc(mx));
}

__global__ void k_hist(const int* __restrict__ ei, int* __restrict__ cnt, int E){
  int i = blockIdx.x * blockDim.x + threadIdx.x;
  if (i < E) atomicAdd(&cnt[ei[E + i]], 1);
}

// single-workgroup exclusive scan (1024 threads, shfl-based) -> row_start, cursor
__global__ void k_scan(const int* __restrict__ cnt, int* __restrict__ rs,
                       int* __restrict__ cursor, int n){
  __shared__ int wsum[16];
  __shared__ int carry_s;
  int lane = threadIdx.x & 63, wid = threadIdx.x >> 6;
  if (threadIdx.x == 0) carry_s = 0;
  __syncthreads();
  for (int base = 0; base < n; base += 1024){
    int i = base + (int)threadIdx.x;
    int v = (i < n) ? cnt[i] : 0;
    int x = v;
    #pragma unroll
    for (int off = 1; off < 64; off <<= 1){
      int t = __shfl_up(x, off, 64);
      if (lane >= off) x += t;
    }
    if (lane == 63) wsum[wid] = x;
    __syncthreads();
    if (wid == 0 && lane < 16){
      int w = wsum[lane];
      #pragma unroll
      for (int off = 1; off < 16; off <<= 1){
        int t = __shfl_up(w, off, 64);
        if (lane >= off) w += t;
      }
      wsum[lane] = w;
    }
    __syncthreads();
    int carry = carry_s;
    int prefix = carry + (wid ? wsum[wid - 1] : 0);
    if (i < n){ int excl = prefix + x - v; rs[i] = excl; cursor[i] = excl; }
    __syncthreads();
    if (threadIdx.x == 1023) carry_s = carry + wsum[15];
    __syncthreads();
  }
  if (threadIdx.x == 0) rs[n] = carry_s;
}

__global__ void k_scatter(const int* __restrict__ ei, int* __restrict__ cursor,
                          int* __restrict__ csr, int E, int N){
  int i = blockIdx.x * blockDim.x + threadIdx.x;
  int T = E + N;
  if (i >= T) return;
  int s, d;
  if (i < E){ s = ei[i]; d = ei[E + i]; } else { s = d = i - E; }
  int pos = atomicAdd(&cursor[d], 1);
  csr[pos] = s;
}

// One wave per destination node. Lanes 0-31 handle even-parity edges, 32-63 odd.
// Within a 32-group, lane m owns channels 4m..4m+3 (head m>>3), float4 gather.
// Softmax stabilized by global upper bound M = lrelu(asmax[h] + a_d) -> no pass-1.
// Fuses /den, +bias, ELU, dot W2 -> h2[d]. Zero atomics.
__global__ void k_agg1(const int* __restrict__ csr, const int* __restrict__ rs,
                       const float* __restrict__ as1, const float* __restrict__ ad1,
                       const unsigned* __restrict__ asmaxu,
                       const float4* __restrict__ h1, const float* __restrict__ bias1,
                       const float* __restrict__ W2, float* __restrict__ h2, int N){
  int wv = threadIdx.x >> 6;
  int lane = threadIdx.x & 63;
  int d = blockIdx.x * 4 + wv;
  if (d >= N) return;
  int g = lane >> 5;          // edge parity group
  int m = lane & 31;          // channel group: channels 4m..4m+3
  int h = m >> 3;             // head
  float adh = ad1[d * 4 + h];
  float M = lrelu(fdec(asmaxu[h]) + adh);
  int beg = rs[d], end = rs[d + 1];
  float den = 0.f;
  float a0 = 0.f, a1 = 0.f, a2 = 0.f, a3 = 0.f;
  int j = beg;
  for (; j + 4 <= end; j += 4){
    int sA = csr[j + g];
    int sB = csr[j + 2 + g];
    float eA = lrelu(as1[sA * 4 + h] + adh);
    float eB = lrelu(as1[sB * 4 + h] + adh);
    float pA = __expf(eA - M);
    float pB = __expf(eB - M);
    float4 hA = h1[(size_t)sA * 32 + m];
    float4 hB = h1[(size_t)sB * 32 + m];
    den += pA + pB;
    a0 = fmaf(pA, hA.x, a0); a1 = fmaf(pA, hA.y, a1);
    a2 = fmaf(pA, hA.z, a2); a3 = fmaf(pA, hA.w, a3);
    a0 = fmaf(pB, hB.x, a0); a1 = fmaf(pB, hB.y, a1);
    a2 = fmaf(pB, hB.z, a2); a3 = fmaf(pB, hB.w, a3);
  }
  for (; j < end; j += 2){
    int slot = j + g;
    bool v = slot < end;
    int s = v ? csr[slot] : csr[beg];
    float e = lrelu(as1[s * 4 + h] + adh);
    float p = v ? __expf(e - M) : 0.f;
    float4 hv = h1[(size_t)s * 32 + m];
    den += p;
    a0 = fmaf(p, hv.x, a0); a1 = fmaf(p, hv.y, a1);
    a2 = fmaf(p, hv.z, a2); a3 = fmaf(p, hv.w, a3);
  }
  // combine edge parities (lane l <-> l^32 hold the same channels)
  a0 += __shfl_xor(a0, 32); a1 += __shfl_xor(a1, 32);
  a2 += __shfl_xor(a2, 32); a3 += __shfl_xor(a3, 32);
  den += __shfl_xor(den, 32);
  float part = 0.f;
  if (lane < 32){
    float invden = 1.f / den;
    float4 bv = ((const float4*)bias1)[m];
    float4 wv2 = ((const float4*)W2)[m];
    float o0 = elu1(a0 * invden + bv.x);
    float o1 = elu1(a1 * invden + bv.y);
    float o2 = elu1(a2 * invden + bv.z);
    float o3 = elu1(a3 * invden + bv.w);
    part = o0 * wv2.x + o1 * wv2.y + o2 * wv2.z + o3 * wv2.w;
  }
  #pragma unroll
  for (int off = 16; off; off >>= 1) part += __shfl_down(part, off);
  if (lane == 0) h2[d] = part;
}

// Layer 2: one wave per destination, lanes strided over its edge list.
// h2 is [N] floats (200 KB, L2-resident). Writes final output.
__global__ void k_agg2(const int* __restrict__ csr, const int* __restrict__ rs,
                       const float* __restrict__ h2,
                       const float* __restrict__ as2p, const float* __restrict__ ad2p,
                       const float* __restrict__ bias2, float* __restrict__ out, int N){
  int wv = threadIdx.x >> 6;
  int lane = threadIdx.x & 63;
  int d = blockIdx.x * 4 + wv;
  if (d >= N) return;
  float asc = as2p[0];
  float hd = h2[d] * ad2p[0];
  int beg = rs[d], end = rs[d + 1];
  float m = -INFINITY;
  for (int j = beg + lane; j < end; j += 64){
    float e = lrelu(h2[csr[j]] * asc + hd);
    m = fmaxf(m, e);
  }
  #pragma unroll
  for (int off = 32; off; off >>= 1) m = fmaxf(m, __shfl_xor(m, off));
  float den = 0.f, acc = 0.f;
  for (int j = beg + lane; j < end; j += 64){
    float hs = h2[csr[j]];
    float e = lrelu(hs * asc + hd);
    float p = __expf(e - m);
    den += p;
    acc = fmaf(p, hs, acc);
  }
  #pragma unroll
  for (int off = 32; off; off >>= 1){
    den += __shfl_xor(den, off);
    acc += __shfl_xor(acc, off);
  }
  if (lane == 0) out[d] = acc / den + bias2[0];
}

extern "C" void kernel_launch(void* const* d_in, const int* in_sizes, int n_in,
                              void* d_out, int out_size, void* d_ws, size_t ws_size,
                              hipStream_t stream){
  const float* x     = (const float*)d_in[0];
  const int*   ei    = (const int*)  d_in[1];
  const float* W1    = (const float*)d_in[2];
  const float* atts1 = (const float*)d_in[3];
  const float* attd1 = (const float*)d_in[4];
  const float* bias1 = (const float*)d_in[5];
  const float* W2    = (const float*)d_in[6];
  const float* atts2 = (const float*)d_in[7];
  const float* attd2 = (const float*)d_in[8];
  const float* bias2 = (const float*)d_in[9];

  int N = in_sizes[0] / 128;   // D = 128
  int E = in_sizes[1] / 2;

  // workspace layout (fp32 units)
  float*    h1   = (float*)d_ws;                       // N*128
  float*    as1  = h1  + (size_t)N * 128;              // N*4
  float*    ad1  = as1 + (size_t)N * 4;                // N*4
  float*    h2   = ad1 + (size_t)N * 4;                // N
  int*      cnt  = (int*)(h2 + N);                     // N
  int*      rs   = cnt + N;                            // N+1
  int*      cursor = rs + N + 1;                       // N
  int*      csr  = cursor + N;                         // E+N
  unsigned* asmaxu = (unsigned*)(csr + E + N);         // 4

  int T = E + N;
  k_init    <<<(N + 255) / 256, 256, 0, stream>>>(cnt, asmaxu, N);
  k_hist    <<<(E + 255) / 256, 256, 0, stream>>>(ei, cnt, E);
  k_scan    <<<1, 1024, 0, stream>>>(cnt, rs, cursor, N);
  k_gemm1   <<<(N + 7) / 8, 256, 0, stream>>>(x, W1, atts1, attd1, h1, as1, ad1, N);
  k_asmax   <<<64, 256, 0, stream>>>(as1, asmaxu, N * 4);
  k_scatter <<<(T + 255) / 256, 256, 0, stream>>>(ei, cursor, csr, E, N);
  k_agg1    <<<(N + 3) / 4, 256, 0, stream>>>(csr, rs, as1, ad1, asmaxu, (const float4*)h1, bias1, W2, h2, N);
  k_agg2    <<<(N + 3) / 4, 256, 0, stream>>>(csr, rs, h2, atts2, attd2, bias2, (float*)d_out, N);
}

// Round 4
// 400.160 us; speedup vs baseline: 3.7905x; 1.2123x over previous
//
#include <hip/hip_runtime.h>
#include <hip/hip_fp16.h>

#define NEG_SLOPE 0.2f
#define BSHIFT 7          // bucket = dst >> 7  (128 dsts per bucket)
#define NB 256            // blocks in bucket hist/scatter passes

__device__ __forceinline__ float lrelu(float x){ return x > 0.f ? x : NEG_SLOPE * x; }
__device__ __forceinline__ float elu1(float x){ return x > 0.f ? x : expm1f(x); }
// float -> ordered uint encoding for atomicMax over signed floats
__device__ __forceinline__ unsigned fenc(float f){
  unsigned u = __float_as_uint(f);
  return (u & 0x80000000u) ? ~u : (u | 0x80000000u);
}
__device__ __forceinline__ float fdec(unsigned u){
  return (u & 0x80000000u) ? __uint_as_float(u & 0x7fffffffu) : __uint_as_float(~u);
}

__global__ void k_init(unsigned* asmaxu, unsigned* h2mm){
  int i = threadIdx.x;
  if (i < 4) asmaxu[i] = 0u;
  if (i < 2) h2mm[i] = 0u;
}

// h1 = x @ W1 (fp16 out), fused a_s/a_d row dots (fp32).
// Block: 256 threads = 8 rows; thread t -> row (t>>5), cols 4*(t&31)..+3.
__global__ void k_gemm1(const float* __restrict__ x, const float* __restrict__ W1,
                        const float* __restrict__ atts, const float* __restrict__ attd,
                        __half* __restrict__ h1, float* __restrict__ as1, float* __restrict__ ad1,
                        int N){
  __shared__ float xs[8][128];
  int n0 = blockIdx.x * 8;
  int t = threadIdx.x;
  #pragma unroll
  for (int i = 0; i < 4; ++i){
    int idx = t + i * 256;
    int r = idx >> 7, c = idx & 127;
    int n = n0 + r;
    xs[r][c] = (n < N) ? x[(size_t)n * 128 + c] : 0.f;
  }
  __syncthreads();
  int m = t & 31, r = t >> 5;
  const float4* W14 = (const float4*)W1;
  float a0 = 0.f, a1 = 0.f, a2 = 0.f, a3 = 0.f;
  #pragma unroll 4
  for (int k = 0; k < 128; ++k){
    float4 w = W14[k * 32 + m];
    float xv = xs[r][k];
    a0 = fmaf(xv, w.x, a0);
    a1 = fmaf(xv, w.y, a1);
    a2 = fmaf(xv, w.z, a2);
    a3 = fmaf(xv, w.w, a3);
  }
  int n = n0 + r;
  if (n < N){
    union { __half2 h[2]; float2 f; } u;
    u.h[0] = __floats2half2_rn(a0, a1);
    u.h[1] = __floats2half2_rn(a2, a3);
    ((float2*)(h1 + (size_t)n * 128))[m] = u.f;
  }
  float4 av = ((const float4*)atts)[m];
  float4 dv = ((const float4*)attd)[m];
  float s  = a0 * av.x + a1 * av.y + a2 * av.z + a3 * av.w;
  float dd = a0 * dv.x + a1 * dv.y + a2 * dv.z + a3 * dv.w;
  #pragma unroll
  for (int off = 4; off; off >>= 1){
    s  += __shfl_down(s, off);
    dd += __shfl_down(dd, off);
  }
  if ((m & 7) == 0 && n < N){
    as1[n * 4 + (m >> 3)] = s;
    ad1[n * 4 + (m >> 3)] = dd;
  }
}

// global per-head max of a_s (upper bound for layer-1 softmax stabilization)
__global__ void k_asmax(const float* __restrict__ as1, unsigned* __restrict__ asmaxu, int N4){
  float mx = -INFINITY;
  for (int i = blockIdx.x * blockDim.x + threadIdx.x; i < N4; i += gridDim.x * blockDim.x)
    mx = fmaxf(mx, as1[i]);
  #pragma unroll
  for (int off = 4; off < 64; off <<= 1) mx = fmaxf(mx, __shfl_xor(mx, off));
  if ((threadIdx.x & 63) < 4) atomicMax(&asmaxu[(threadIdx.x & 3)], fenc(mx));
}

// ---- CSR build: 2-level counting sort, LDS atomics only ----

// Pass A: per-block bucket histogram
__global__ void k_bhist(const int* __restrict__ ei, int* __restrict__ gcnt,
                        int E, int N, int B, int chunk){
  __shared__ int hist[512];
  for (int t = threadIdx.x; t < B; t += 256) hist[t] = 0;
  __syncthreads();
  int T = E + N;
  int lo = blockIdx.x * chunk;
  int hi = min(lo + chunk, T);
  for (int i = lo + (int)threadIdx.x; i < hi; i += 256){
    int d = (i < E) ? ei[E + i] : (i - E);
    atomicAdd(&hist[d >> BSHIFT], 1);
  }
  __syncthreads();
  for (int t = threadIdx.x; t < B; t += 256) gcnt[blockIdx.x * B + t] = hist[t];
}

// Pass B: flat exclusive scan over (bucket-major, block-minor) counts
__global__ void k_bscan(const int* __restrict__ gcnt, int* __restrict__ ecur, int B){
  __shared__ int wsum[16];
  __shared__ int carry_s;
  int lane = threadIdx.x & 63, wid = threadIdx.x >> 6;
  if (threadIdx.x == 0) carry_s = 0;
  __syncthreads();
  int L = NB * B;
  for (int base = 0; base < L; base += 1024){
    int i = base + (int)threadIdx.x;
    int v = 0;
    if (i < L){
      int b = i >> 8;          // i / NB  (NB==256)
      int blk = i & 255;
      v = gcnt[blk * B + b];
    }
    int x = v;
    #pragma unroll
    for (int off = 1; off < 64; off <<= 1){
      int t = __shfl_up(x, off, 64);
      if (lane >= off) x += t;
    }
    if (lane == 63) wsum[wid] = x;
    __syncthreads();
    if (wid == 0 && lane < 16){
      int w = wsum[lane];
      #pragma unroll
      for (int off = 1; off < 16; off <<= 1){
        int t = __shfl_up(w, off, 64);
        if (lane >= off) w += t;
      }
      wsum[lane] = w;
    }
    __syncthreads();
    int carry = carry_s;
    int prefix = carry + (wid ? wsum[wid - 1] : 0);
    if (i < L) ecur[i] = prefix + x - v;
    __syncthreads();
    if (threadIdx.x == 1023) carry_s = carry + wsum[15];
    __syncthreads();
  }
}

// Pass C: scatter (src,dst) pairs into bucket-partitioned ebuf; per-block
// private contiguous ranges -> ~sequential writes; LDS cursors only.
__global__ void k_bscatter(const int* __restrict__ ei, const int* __restrict__ ecur,
                           unsigned long long* __restrict__ ebuf,
                           int E, int N, int B, int chunk){
  __shared__ int cur[512];
  for (int t = threadIdx.x; t < B; t += 256) cur[t] = ecur[t * NB + blockIdx.x];
  __syncthreads();
  int T = E + N;
  int lo = blockIdx.x * chunk;
  int hi = min(lo + chunk, T);
  for (int i = lo + (int)threadIdx.x; i < hi; i += 256){
    int s, d;
    if (i < E){ s = ei[i]; d = ei[E + i]; } else { s = d = i - E; }
    int pos = atomicAdd(&cur[d >> BSHIFT], 1);
    ebuf[pos] = ((unsigned long long)(unsigned)d << 32) | (unsigned)s;
  }
}

// Pass D: one block per bucket; LDS 128-dst hist + scan -> rs + final csr
__global__ void k_bfinal(const unsigned long long* __restrict__ ebuf,
                         const int* __restrict__ ecur,
                         int* __restrict__ csr, int* __restrict__ rs,
                         int N, int B, int T){
  int b = blockIdx.x;
  int d0 = b << BSHIFT;
  int dcount = min(128, N - d0);
  int ebeg = ecur[b * NB];
  int eend = (b + 1 < B) ? ecur[(b + 1) * NB] : T;
  __shared__ int hist[128];
  __shared__ int excl[128];
  if (threadIdx.x < 128) hist[threadIdx.x] = 0;
  __syncthreads();
  for (int i = ebeg + (int)threadIdx.x; i < eend; i += 256)
    atomicAdd(&hist[(int)(ebuf[i] >> 32) - d0], 1);
  __syncthreads();
  if (threadIdx.x < 64){
    int l = threadIdx.x;
    int v0 = hist[l], v1 = hist[l + 64];
    int s0 = v0, s1 = v1;
    #pragma unroll
    for (int off = 1; off < 64; off <<= 1){
      int t0 = __shfl_up(s0, off, 64); if (l >= off) s0 += t0;
      int t1 = __shfl_up(s1, off, 64); if (l >= off) s1 += t1;
    }
    int tot0 = __shfl(s0, 63, 64);
    excl[l] = s0 - v0;
    excl[l + 64] = tot0 + s1 - v1;
  }
  __syncthreads();
  if (threadIdx.x < dcount) rs[d0 + threadIdx.x] = ebeg + excl[threadIdx.x];
  if (threadIdx.x < 128) hist[threadIdx.x] = excl[threadIdx.x];  // -> cursor
  if (b == 0 && threadIdx.x == 255) rs[N] = T;
  __syncthreads();
  for (int i = ebeg + (int)threadIdx.x; i < eend; i += 256){
    unsigned long long e = ebuf[i];
    int d = (int)(e >> 32);
    int pos = ebeg + atomicAdd(&hist[d - d0], 1);
    csr[pos] = (int)(e & 0xFFFFFFFFu);
  }
}

// ---- Layer 1 aggregation: one wave per dst, 16 lanes per edge (8 fp16 ch/lane),
// 4 edges in flight. Softmax via global upper bound (no max pass). Fuses
// /den, +bias, ELU, dot W2 -> h2[d]. Zero atomics.
__global__ void k_agg1(const int* __restrict__ csr, const int* __restrict__ rs,
                       const float* __restrict__ as1, const float* __restrict__ ad1,
                       const unsigned* __restrict__ asmaxu,
                       const float4* __restrict__ h1,
                       const float* __restrict__ bias1,
                       const float* __restrict__ W2, float* __restrict__ h2, int N){
  int wv = threadIdx.x >> 6;
  int lane = threadIdx.x & 63;
  int d = blockIdx.x * 4 + wv;
  if (d >= N) return;
  int g = lane >> 4;          // edge subgroup 0..3
  int m = lane & 15;          // channels 8m..8m+7
  int h = m >> 2;             // head
  float adh = ad1[d * 4 + h];
  float M = lrelu(fdec(asmaxu[h]) + adh);
  int beg = rs[d], end = rs[d + 1];
  float den = 0.f;
  float a0=0.f,a1=0.f,a2=0.f,a3=0.f,a4=0.f,a5=0.f,a6=0.f,a7=0.f;
  for (int j = beg; j < end; j += 4){
    int slot = j + g;
    bool v = slot < end;
    int s = csr[v ? slot : beg];
    float e = lrelu(as1[s * 4 + h] + adh);
    float p = v ? __expf(e - M) : 0.f;
    float4 raw = h1[(size_t)s * 16 + m];
    float2 c01 = __half22float2(*(__half2*)&raw.x);
    float2 c23 = __half22float2(*(__half2*)&raw.y);
    float2 c45 = __half22float2(*(__half2*)&raw.z);
    float2 c67 = __half22float2(*(__half2*)&raw.w);
    den += p;
    a0 = fmaf(p, c01.x, a0); a1 = fmaf(p, c01.y, a1);
    a2 = fmaf(p, c23.x, a2); a3 = fmaf(p, c23.y, a3);
    a4 = fmaf(p, c45.x, a4); a5 = fmaf(p, c45.y, a5);
    a6 = fmaf(p, c67.x, a6); a7 = fmaf(p, c67.y, a7);
  }
  #define CMB(v) v += __shfl_xor(v, 16); v += __shfl_xor(v, 32);
  CMB(a0) CMB(a1) CMB(a2) CMB(a3) CMB(a4) CMB(a5) CMB(a6) CMB(a7) CMB(den)
  #undef CMB
  float part = 0.f;
  if (lane < 16){
    float invden = 1.f / den;
    float4 b03 = ((const float4*)bias1)[2 * m];
    float4 b47 = ((const float4*)bias1)[2 * m + 1];
    float4 w03 = ((const float4*)W2)[2 * m];
    float4 w47 = ((const float4*)W2)[2 * m + 1];
    part  = elu1(a0 * invden + b03.x) * w03.x;
    part += elu1(a1 * invden + b03.y) * w03.y;
    part += elu1(a2 * invden + b03.z) * w03.z;
    part += elu1(a3 * invden + b03.w) * w03.w;
    part += elu1(a4 * invden + b47.x) * w47.x;
    part += elu1(a5 * invden + b47.y) * w47.y;
    part += elu1(a6 * invden + b47.z) * w47.z;
    part += elu1(a7 * invden + b47.w) * w47.w;
  }
  #pragma unroll
  for (int off = 8; off; off >>= 1) part += __shfl_down(part, off);
  if (lane == 0) h2[d] = part;
}

// global min/max of h2 (upper bound inputs for layer-2 softmax)
__global__ void k_h2mm(const float* __restrict__ h2, unsigned* __restrict__ h2mm, int N){
  float mx = -INFINITY, mn = INFINITY;
  for (int i = blockIdx.x * blockDim.x + threadIdx.x; i < N; i += gridDim.x * blockDim.x){
    float v = h2[i];
    mx = fmaxf(mx, v); mn = fminf(mn, v);
  }
  #pragma unroll
  for (int off = 1; off < 64; off <<= 1){
    mx = fmaxf(mx, __shfl_xor(mx, off));
    mn = fminf(mn, __shfl_xor(mn, off));
  }
  if ((threadIdx.x & 63) == 0){
    atomicMax(&h2mm[0], fenc(mx));
    atomicMax(&h2mm[1], fenc(-mn));
  }
}

// Layer 2: one wave per dst, single pass (bound-stabilized softmax).
__global__ void k_agg2(const int* __restrict__ csr, const int* __restrict__ rs,
                       const float* __restrict__ h2, const unsigned* __restrict__ h2mm,
                       const float* __restrict__ as2p, const float* __restrict__ ad2p,
                       const float* __restrict__ bias2, float* __restrict__ out, int N){
  int wv = threadIdx.x >> 6;
  int lane = threadIdx.x & 63;
  int d = blockIdx.x * 4 + wv;
  if (d >= N) return;
  float asc = as2p[0];
  float hmax = fdec(h2mm[0]), hmn = -fdec(h2mm[1]);
  float bound = (asc >= 0.f) ? asc * hmax : asc * hmn;
  float hd = h2[d] * ad2p[0];
  float M = lrelu(bound + hd);
  int beg = rs[d], end = rs[d + 1];
  float den = 0.f, acc = 0.f;
  for (int j = beg + lane; j < end; j += 64){
    float hs = h2[csr[j]];
    float p = __expf(lrelu(hs * asc + hd) - M);
    den += p;
    acc = fmaf(p, hs, acc);
  }
  #pragma unroll
  for (int off = 32; off; off >>= 1){
    den += __shfl_xor(den, off);
    acc += __shfl_xor(acc, off);
  }
  if (lane == 0) out[d] = acc / den + bias2[0];
}

extern "C" void kernel_launch(void* const* d_in, const int* in_sizes, int n_in,
                              void* d_out, int out_size, void* d_ws, size_t ws_size,
                              hipStream_t stream){
  const float* x     = (const float*)d_in[0];
  const int*   ei    = (const int*)  d_in[1];
  const float* W1    = (const float*)d_in[2];
  const float* atts1 = (const float*)d_in[3];
  const float* attd1 = (const float*)d_in[4];
  const float* bias1 = (const float*)d_in[5];
  const float* W2    = (const float*)d_in[6];
  const float* atts2 = (const float*)d_in[7];
  const float* attd2 = (const float*)d_in[8];
  const float* bias2 = (const float*)d_in[9];

  int N = in_sizes[0] / 128;   // D = 128
  int E = in_sizes[1] / 2;
  int T = E + N;
  int B = (N + 127) >> BSHIFT;           // dst buckets of 128
  int chunk = (T + NB - 1) / NB;

  // workspace layout (bytes)
  char* p = (char*)d_ws;
  unsigned long long* ebuf = (unsigned long long*)p; p += (size_t)T * 8;
  __half* h1   = (__half*)p;  p += (size_t)N * 128 * 2;
  float*  as1  = (float*)p;   p += (size_t)N * 4 * 4;
  float*  ad1  = (float*)p;   p += (size_t)N * 4 * 4;
  float*  h2   = (float*)p;   p += (size_t)N * 4;
  int*    gcnt = (int*)p;     p += (size_t)NB * B * 4;
  int*    ecur = (int*)p;     p += (size_t)NB * B * 4;
  int*    csr  = (int*)p;     p += (size_t)T * 4;
  int*    rs   = (int*)p;     p += (size_t)(N + 1) * 4;
  unsigned* asmaxu = (unsigned*)p; p += 4 * 4;
  unsigned* h2mm   = (unsigned*)p;

  k_init    <<<1, 64, 0, stream>>>(asmaxu, h2mm);
  k_gemm1   <<<(N + 7) / 8, 256, 0, stream>>>(x, W1, atts1, attd1, h1, as1, ad1, N);
  k_asmax   <<<64, 256, 0, stream>>>(as1, asmaxu, N * 4);
  k_bhist   <<<NB, 256, 0, stream>>>(ei, gcnt, E, N, B, chunk);
  k_bscan   <<<1, 1024, 0, stream>>>(gcnt, ecur, B);
  k_bscatter<<<NB, 256, 0, stream>>>(ei, ecur, ebuf, E, N, B, chunk);
  k_bfinal  <<<B, 256, 0, stream>>>(ebuf, ecur, csr, rs, N, B, T);
  k_agg1    <<<(N + 3) / 4, 256, 0, stream>>>(csr, rs, as1, ad1, asmaxu,
                                              (const float4*)h1, bias1, W2, h2, N);
  k_h2mm    <<<64, 256, 0, stream>>>(h2, h2mm, N);
  k_agg2    <<<(N + 3) / 4, 256, 0, stream>>>(csr, rs, h2, h2mm, atts2, attd2,
                                              bias2, (float*)d_out, N);
}

// Round 5
// 249.867 us; speedup vs baseline: 6.0705x; 1.6015x over previous
//
#include <hip/hip_runtime.h>
#include <hip/hip_fp16.h>

#define NEG_SLOPE 0.2f
#define BSHIFT 7          // bucket = dst >> 7  (128 dsts per bucket)
#define NB 256            // blocks in bucket hist/scatter passes

__device__ __forceinline__ float lrelu(float x){ return x > 0.f ? x : NEG_SLOPE * x; }
__device__ __forceinline__ float elu1(float x){ return x > 0.f ? x : expm1f(x); }
// float -> ordered uint encoding for atomicMax over signed floats
__device__ __forceinline__ unsigned fenc(float f){
  unsigned u = __float_as_uint(f);
  return (u & 0x80000000u) ? ~u : (u | 0x80000000u);
}
__device__ __forceinline__ float fdec(unsigned u){
  return (u & 0x80000000u) ? __uint_as_float(u & 0x7fffffffu) : __uint_as_float(~u);
}

__global__ void k_init(unsigned* asmaxu, unsigned* h2mm){
  int i = threadIdx.x;
  if (i < 4) asmaxu[i] = 0u;
  if (i < 2) h2mm[i] = 0u;
}

// h1 = x @ W1 (fp16 out), fused a_s/a_d row dots (fp32).
__global__ void k_gemm1(const float* __restrict__ x, const float* __restrict__ W1,
                        const float* __restrict__ atts, const float* __restrict__ attd,
                        __half* __restrict__ h1, float* __restrict__ as1, float* __restrict__ ad1,
                        int N){
  __shared__ float xs[8][128];
  int n0 = blockIdx.x * 8;
  int t = threadIdx.x;
  #pragma unroll
  for (int i = 0; i < 4; ++i){
    int idx = t + i * 256;
    int r = idx >> 7, c = idx & 127;
    int n = n0 + r;
    xs[r][c] = (n < N) ? x[(size_t)n * 128 + c] : 0.f;
  }
  __syncthreads();
  int m = t & 31, r = t >> 5;
  const float4* W14 = (const float4*)W1;
  float a0 = 0.f, a1 = 0.f, a2 = 0.f, a3 = 0.f;
  #pragma unroll 4
  for (int k = 0; k < 128; ++k){
    float4 w = W14[k * 32 + m];
    float xv = xs[r][k];
    a0 = fmaf(xv, w.x, a0);
    a1 = fmaf(xv, w.y, a1);
    a2 = fmaf(xv, w.z, a2);
    a3 = fmaf(xv, w.w, a3);
  }
  int n = n0 + r;
  if (n < N){
    union { __half2 h[2]; float2 f; } u;
    u.h[0] = __floats2half2_rn(a0, a1);
    u.h[1] = __floats2half2_rn(a2, a3);
    ((float2*)(h1 + (size_t)n * 128))[m] = u.f;
  }
  float4 av = ((const float4*)atts)[m];
  float4 dv = ((const float4*)attd)[m];
  float s  = a0 * av.x + a1 * av.y + a2 * av.z + a3 * av.w;
  float dd = a0 * dv.x + a1 * dv.y + a2 * dv.z + a3 * dv.w;
  #pragma unroll
  for (int off = 4; off; off >>= 1){
    s  += __shfl_down(s, off);
    dd += __shfl_down(dd, off);
  }
  if ((m & 7) == 0 && n < N){
    as1[n * 4 + (m >> 3)] = s;
    ad1[n * 4 + (m >> 3)] = dd;
  }
}

// global per-head max of a_s (upper bound for layer-1 softmax stabilization)
__global__ void k_asmax(const float* __restrict__ as1, unsigned* __restrict__ asmaxu, int N4){
  float mx = -INFINITY;
  for (int i = blockIdx.x * blockDim.x + threadIdx.x; i < N4; i += gridDim.x * blockDim.x)
    mx = fmaxf(mx, as1[i]);
  #pragma unroll
  for (int off = 4; off < 64; off <<= 1) mx = fmaxf(mx, __shfl_xor(mx, off));
  if ((threadIdx.x & 63) < 4) atomicMax(&asmaxu[(threadIdx.x & 3)], fenc(mx));
}

// ---- CSR build: 2-level counting sort, LDS atomics only ----

// Pass A: per-block bucket histogram
__global__ void k_bhist(const int* __restrict__ ei, int* __restrict__ gcnt,
                        int E, int N, int B, int chunk){
  __shared__ int hist[512];
  for (int t = threadIdx.x; t < B; t += 256) hist[t] = 0;
  __syncthreads();
  int T = E + N;
  int lo = blockIdx.x * chunk;
  int hi = min(lo + chunk, T);
  for (int i = lo + (int)threadIdx.x; i < hi; i += 256){
    int d = (i < E) ? ei[E + i] : (i - E);
    atomicAdd(&hist[d >> BSHIFT], 1);
  }
  __syncthreads();
  for (int t = threadIdx.x; t < B; t += 256) gcnt[blockIdx.x * B + t] = hist[t];
}

// Pass B1: one block per bucket — scan its 256 per-block counts.
// ecur[b*NB+blk] = LOCAL exclusive prefix; btot[b] = bucket total.
__global__ void k_bprefix(const int* __restrict__ gcnt, int* __restrict__ ecur,
                          int* __restrict__ btot, int B){
  int b = blockIdx.x;
  int t = threadIdx.x;            // = source block id
  int v = gcnt[t * B + b];
  int lane = t & 63, wid = t >> 6;
  int x = v;
  #pragma unroll
  for (int off = 1; off < 64; off <<= 1){
    int tmp = __shfl_up(x, off, 64);
    if (lane >= off) x += tmp;
  }
  __shared__ int ws[4];
  if (lane == 63) ws[wid] = x;
  __syncthreads();
  if (t == 0){
    int s = 0;
    #pragma unroll
    for (int i = 0; i < 4; ++i){ int tmp = ws[i]; ws[i] = s; s += tmp; }
  }
  __syncthreads();
  int excl = ws[wid] + x - v;
  ecur[b * NB + t] = excl;
  if (t == 255) btot[b] = excl + v;
}

// Pass B2: single block — exclusive scan of the B bucket totals -> bstart.
__global__ void k_btscan(const int* __restrict__ btot, int* __restrict__ bstart,
                         int B, int T){
  __shared__ int wsum[16];
  __shared__ int carry_s;
  int lane = threadIdx.x & 63, wid = threadIdx.x >> 6;
  if (threadIdx.x == 0) carry_s = 0;
  __syncthreads();
  for (int base = 0; base < B; base += 1024){
    int i = base + (int)threadIdx.x;
    int v = (i < B) ? btot[i] : 0;
    int x = v;
    #pragma unroll
    for (int off = 1; off < 64; off <<= 1){
      int t = __shfl_up(x, off, 64);
      if (lane >= off) x += t;
    }
    if (lane == 63) wsum[wid] = x;
    __syncthreads();
    if (wid == 0 && lane < 16){
      int w = wsum[lane];
      #pragma unroll
      for (int off = 1; off < 16; off <<= 1){
        int t = __shfl_up(w, off, 64);
        if (lane >= off) w += t;
      }
      wsum[lane] = w;
    }
    __syncthreads();
    int carry = carry_s;
    int prefix = carry + (wid ? wsum[wid - 1] : 0);
    if (i < B) bstart[i] = prefix + x - v;
    __syncthreads();
    if (threadIdx.x == 1023) carry_s = carry + wsum[15];
    __syncthreads();
  }
  if (threadIdx.x == 0) bstart[B] = T;
}

// Pass C: scatter (src,dst) pairs into bucket-partitioned ebuf; per-block
// private contiguous ranges -> ~sequential writes; LDS cursors only.
__global__ void k_bscatter(const int* __restrict__ ei, const int* __restrict__ ecur,
                           const int* __restrict__ bstart,
                           unsigned long long* __restrict__ ebuf,
                           int E, int N, int B, int chunk){
  __shared__ int cur[512];
  for (int t = threadIdx.x; t < B; t += 256)
    cur[t] = ecur[t * NB + blockIdx.x] + bstart[t];
  __syncthreads();
  int T = E + N;
  int lo = blockIdx.x * chunk;
  int hi = min(lo + chunk, T);
  for (int i = lo + (int)threadIdx.x; i < hi; i += 256){
    int s, d;
    if (i < E){ s = ei[i]; d = ei[E + i]; } else { s = d = i - E; }
    int pos = atomicAdd(&cur[d >> BSHIFT], 1);
    ebuf[pos] = ((unsigned long long)(unsigned)d << 32) | (unsigned)s;
  }
}

// Pass D: one block per bucket; LDS 128-dst hist + scan -> rs + final csr
__global__ void k_bfinal(const unsigned long long* __restrict__ ebuf,
                         const int* __restrict__ bstart,
                         int* __restrict__ csr, int* __restrict__ rs,
                         int N, int B, int T){
  int b = blockIdx.x;
  int d0 = b << BSHIFT;
  int dcount = min(128, N - d0);
  int ebeg = bstart[b];
  int eend = bstart[b + 1];
  __shared__ int hist[128];
  __shared__ int excl[128];
  if (threadIdx.x < 128) hist[threadIdx.x] = 0;
  __syncthreads();
  for (int i = ebeg + (int)threadIdx.x; i < eend; i += 256)
    atomicAdd(&hist[(int)(ebuf[i] >> 32) - d0], 1);
  __syncthreads();
  if (threadIdx.x < 64){
    int l = threadIdx.x;
    int v0 = hist[l], v1 = hist[l + 64];
    int s0 = v0, s1 = v1;
    #pragma unroll
    for (int off = 1; off < 64; off <<= 1){
      int t0 = __shfl_up(s0, off, 64); if (l >= off) s0 += t0;
      int t1 = __shfl_up(s1, off, 64); if (l >= off) s1 += t1;
    }
    int tot0 = __shfl(s0, 63, 64);
    excl[l] = s0 - v0;
    excl[l + 64] = tot0 + s1 - v1;
  }
  __syncthreads();
  if (threadIdx.x < dcount) rs[d0 + threadIdx.x] = ebeg + excl[threadIdx.x];
  if (threadIdx.x < 128) hist[threadIdx.x] = excl[threadIdx.x];  // -> cursor
  if (b == 0 && threadIdx.x == 255) rs[N] = T;
  __syncthreads();
  for (int i = ebeg + (int)threadIdx.x; i < eend; i += 256){
    unsigned long long e = ebuf[i];
    int d = (int)(e >> 32);
    int pos = ebeg + atomicAdd(&hist[d - d0], 1);
    csr[pos] = (int)(e & 0xFFFFFFFFu);
  }
}

// ---- Layer 1 aggregation: one wave per dst, 16 lanes per edge (8 fp16 ch/lane),
// 4 edges in flight. Softmax via global upper bound (no max pass). Fuses
// /den, +bias, ELU, dot W2 -> h2[d]. Zero atomics.
__global__ void k_agg1(const int* __restrict__ csr, const int* __restrict__ rs,
                       const float* __restrict__ as1, const float* __restrict__ ad1,
                       const unsigned* __restrict__ asmaxu,
                       const float4* __restrict__ h1,
                       const float* __restrict__ bias1,
                       const float* __restrict__ W2, float* __restrict__ h2, int N){
  int wv = threadIdx.x >> 6;
  int lane = threadIdx.x & 63;
  int d = blockIdx.x * 4 + wv;
  if (d >= N) return;
  int g = lane >> 4;          // edge subgroup 0..3
  int m = lane & 15;          // channels 8m..8m+7
  int h = m >> 2;             // head
  float adh = ad1[d * 4 + h];
  float M = lrelu(fdec(asmaxu[h]) + adh);
  int beg = rs[d], end = rs[d + 1];
  float den = 0.f;
  float a0=0.f,a1=0.f,a2=0.f,a3=0.f,a4=0.f,a5=0.f,a6=0.f,a7=0.f;
  for (int j = beg; j < end; j += 4){
    int slot = j + g;
    bool v = slot < end;
    int s = csr[v ? slot : beg];
    float e = lrelu(as1[s * 4 + h] + adh);
    float p = v ? __expf(e - M) : 0.f;
    float4 raw = h1[(size_t)s * 16 + m];
    float2 c01 = __half22float2(*(__half2*)&raw.x);
    float2 c23 = __half22float2(*(__half2*)&raw.y);
    float2 c45 = __half22float2(*(__half2*)&raw.z);
    float2 c67 = __half22float2(*(__half2*)&raw.w);
    den += p;
    a0 = fmaf(p, c01.x, a0); a1 = fmaf(p, c01.y, a1);
    a2 = fmaf(p, c23.x, a2); a3 = fmaf(p, c23.y, a3);
    a4 = fmaf(p, c45.x, a4); a5 = fmaf(p, c45.y, a5);
    a6 = fmaf(p, c67.x, a6); a7 = fmaf(p, c67.y, a7);
  }
  #define CMB(v) v += __shfl_xor(v, 16); v += __shfl_xor(v, 32);
  CMB(a0) CMB(a1) CMB(a2) CMB(a3) CMB(a4) CMB(a5) CMB(a6) CMB(a7) CMB(den)
  #undef CMB
  float part = 0.f;
  if (lane < 16){
    float invden = 1.f / den;
    float4 b03 = ((const float4*)bias1)[2 * m];
    float4 b47 = ((const float4*)bias1)[2 * m + 1];
    float4 w03 = ((const float4*)W2)[2 * m];
    float4 w47 = ((const float4*)W2)[2 * m + 1];
    part  = elu1(a0 * invden + b03.x) * w03.x;
    part += elu1(a1 * invden + b03.y) * w03.y;
    part += elu1(a2 * invden + b03.z) * w03.z;
    part += elu1(a3 * invden + b03.w) * w03.w;
    part += elu1(a4 * invden + b47.x) * w47.x;
    part += elu1(a5 * invden + b47.y) * w47.y;
    part += elu1(a6 * invden + b47.z) * w47.z;
    part += elu1(a7 * invden + b47.w) * w47.w;
  }
  #pragma unroll
  for (int off = 8; off; off >>= 1) part += __shfl_down(part, off);
  if (lane == 0) h2[d] = part;
}

// global min/max of h2 (upper bound inputs for layer-2 softmax)
__global__ void k_h2mm(const float* __restrict__ h2, unsigned* __restrict__ h2mm, int N){
  float mx = -INFINITY, mn = INFINITY;
  for (int i = blockIdx.x * blockDim.x + threadIdx.x; i < N; i += gridDim.x * blockDim.x){
    float v = h2[i];
    mx = fmaxf(mx, v); mn = fminf(mn, v);
  }
  #pragma unroll
  for (int off = 1; off < 64; off <<= 1){
    mx = fmaxf(mx, __shfl_xor(mx, off));
    mn = fminf(mn, __shfl_xor(mn, off));
  }
  if ((threadIdx.x & 63) == 0){
    atomicMax(&h2mm[0], fenc(mx));
    atomicMax(&h2mm[1], fenc(-mn));
  }
}

// Layer 2: one wave per dst, single pass (bound-stabilized softmax).
__global__ void k_agg2(const int* __restrict__ csr, const int* __restrict__ rs,
                       const float* __restrict__ h2, const unsigned* __restrict__ h2mm,
                       const float* __restrict__ as2p, const float* __restrict__ ad2p,
                       const float* __restrict__ bias2, float* __restrict__ out, int N){
  int wv = threadIdx.x >> 6;
  int lane = threadIdx.x & 63;
  int d = blockIdx.x * 4 + wv;
  if (d >= N) return;
  float asc = as2p[0];
  float hmax = fdec(h2mm[0]), hmn = -fdec(h2mm[1]);
  float bound = (asc >= 0.f) ? asc * hmax : asc * hmn;
  float hd = h2[d] * ad2p[0];
  float M = lrelu(bound + hd);
  int beg = rs[d], end = rs[d + 1];
  float den = 0.f, acc = 0.f;
  for (int j = beg + lane; j < end; j += 64){
    float hs = h2[csr[j]];
    float p = __expf(lrelu(hs * asc + hd) - M);
    den += p;
    acc = fmaf(p, hs, acc);
  }
  #pragma unroll
  for (int off = 32; off; off >>= 1){
    den += __shfl_xor(den, off);
    acc += __shfl_xor(acc, off);
  }
  if (lane == 0) out[d] = acc / den + bias2[0];
}

extern "C" void kernel_launch(void* const* d_in, const int* in_sizes, int n_in,
                              void* d_out, int out_size, void* d_ws, size_t ws_size,
                              hipStream_t stream){
  const float* x     = (const float*)d_in[0];
  const int*   ei    = (const int*)  d_in[1];
  const float* W1    = (const float*)d_in[2];
  const float* atts1 = (const float*)d_in[3];
  const float* attd1 = (const float*)d_in[4];
  const float* bias1 = (const float*)d_in[5];
  const float* W2    = (const float*)d_in[6];
  const float* atts2 = (const float*)d_in[7];
  const float* attd2 = (const float*)d_in[8];
  const float* bias2 = (const float*)d_in[9];

  int N = in_sizes[0] / 128;   // D = 128
  int E = in_sizes[1] / 2;
  int T = E + N;
  int B = (N + 127) >> BSHIFT;           // dst buckets of 128
  int chunk = (T + NB - 1) / NB;

  // workspace layout (bytes)
  char* p = (char*)d_ws;
  unsigned long long* ebuf = (unsigned long long*)p; p += (size_t)T * 8;
  __half* h1   = (__half*)p;  p += (size_t)N * 128 * 2;
  float*  as1  = (float*)p;   p += (size_t)N * 4 * 4;
  float*  ad1  = (float*)p;   p += (size_t)N * 4 * 4;
  float*  h2   = (float*)p;   p += (size_t)N * 4;
  int*    gcnt = (int*)p;     p += (size_t)NB * B * 4;
  int*    ecur = (int*)p;     p += (size_t)NB * B * 4;
  int*    csr  = (int*)p;     p += (size_t)T * 4;
  int*    rs   = (int*)p;     p += (size_t)(N + 1) * 4;
  int*    btot = (int*)p;     p += (size_t)B * 4;
  int*    bstart = (int*)p;   p += (size_t)(B + 1) * 4;
  unsigned* asmaxu = (unsigned*)p; p += 4 * 4;
  unsigned* h2mm   = (unsigned*)p;

  k_init    <<<1, 64, 0, stream>>>(asmaxu, h2mm);
  k_gemm1   <<<(N + 7) / 8, 256, 0, stream>>>(x, W1, atts1, attd1, h1, as1, ad1, N);
  k_asmax   <<<64, 256, 0, stream>>>(as1, asmaxu, N * 4);
  k_bhist   <<<NB, 256, 0, stream>>>(ei, gcnt, E, N, B, chunk);
  k_bprefix <<<B, 256, 0, stream>>>(gcnt, ecur, btot, B);
  k_btscan  <<<1, 1024, 0, stream>>>(btot, bstart, B, T);
  k_bscatter<<<NB, 256, 0, stream>>>(ei, ecur, bstart, ebuf, E, N, B, chunk);
  k_bfinal  <<<B, 256, 0, stream>>>(ebuf, bstart, csr, rs, N, B, T);
  k_agg1    <<<(N + 3) / 4, 256, 0, stream>>>(csr, rs, as1, ad1, asmaxu,
                                              (const float4*)h1, bias1, W2, h2, N);
  k_h2mm    <<<64, 256, 0, stream>>>(h2, h2mm, N);
  k_agg2    <<<(N + 3) / 4, 256, 0, stream>>>(csr, rs, h2, h2mm, atts2, attd2,
                                              bias2, (float*)d_out, N);
}

// Round 6
// 187.543 us; speedup vs baseline: 8.0878x; 1.3323x over previous
//
#include <hip/hip_runtime.h>
#include <hip/hip_fp16.h>

#define NEG_SLOPE 0.2f
#define BSHIFT 7          // bucket = dst >> 7  (128 dsts per bucket)
#define NB 256            // blocks in bucket hist/scatter passes

__device__ __forceinline__ float lrelu(float x){ return x > 0.f ? x : NEG_SLOPE * x; }
__device__ __forceinline__ float elu1(float x){ return x > 0.f ? x : expm1f(x); }
// float -> ordered uint encoding for atomicMax over signed floats
__device__ __forceinline__ unsigned fenc(float f){
  unsigned u = __float_as_uint(f);
  return (u & 0x80000000u) ? ~u : (u | 0x80000000u);
}
__device__ __forceinline__ float fdec(unsigned u){
  return (u & 0x80000000u) ? __uint_as_float(u & 0x7fffffffu) : __uint_as_float(~u);
}

__global__ void k_init(unsigned* asmaxu, unsigned* h2mm){
  int i = threadIdx.x;
  if (i < 4) asmaxu[i] = 0u;
  if (i < 2) h2mm[i] = 0u;
}

// h1 = x @ W1 (fp16 out), fused a_s/a_d row dots (fp32).
// 64 rows/block, 256 threads; thread t = 8 rows (r8*8..+7) x 4 cols (4m..4m+3).
// x staged transposed in LDS (pad 4 -> aligned b128 reads, conflict-free).
__global__ __launch_bounds__(256, 4) void k_gemm1(
    const float* __restrict__ x, const float* __restrict__ W1,
    const float* __restrict__ atts, const float* __restrict__ attd,
    __half* __restrict__ h1, float* __restrict__ as1, float* __restrict__ ad1,
    int N){
  __shared__ float xs[128][68];   // [k][row], 34.8 KB
  int n0 = blockIdx.x * 64;
  int t = threadIdx.x;
  #pragma unroll
  for (int i = 0; i < 32; ++i){
    int flat = t + i * 256;
    int row = flat >> 7, c = flat & 127;
    int n = n0 + row;
    xs[c][row] = (n < N) ? x[(size_t)n * 128 + c] : 0.f;
  }
  __syncthreads();
  int m = t & 31, r8 = t >> 5;
  int rowbase = r8 * 8;
  const float4* W14 = (const float4*)W1;
  float4 acc[8];
  #pragma unroll
  for (int rr = 0; rr < 8; ++rr) acc[rr] = make_float4(0.f, 0.f, 0.f, 0.f);
  #pragma unroll 4
  for (int k = 0; k < 128; ++k){
    float4 w = W14[k * 32 + m];
    float4 xa = *(const float4*)&xs[k][rowbase];
    float4 xb = *(const float4*)&xs[k][rowbase + 4];
    acc[0].x = fmaf(xa.x, w.x, acc[0].x); acc[0].y = fmaf(xa.x, w.y, acc[0].y);
    acc[0].z = fmaf(xa.x, w.z, acc[0].z); acc[0].w = fmaf(xa.x, w.w, acc[0].w);
    acc[1].x = fmaf(xa.y, w.x, acc[1].x); acc[1].y = fmaf(xa.y, w.y, acc[1].y);
    acc[1].z = fmaf(xa.y, w.z, acc[1].z); acc[1].w = fmaf(xa.y, w.w, acc[1].w);
    acc[2].x = fmaf(xa.z, w.x, acc[2].x); acc[2].y = fmaf(xa.z, w.y, acc[2].y);
    acc[2].z = fmaf(xa.z, w.z, acc[2].z); acc[2].w = fmaf(xa.z, w.w, acc[2].w);
    acc[3].x = fmaf(xa.w, w.x, acc[3].x); acc[3].y = fmaf(xa.w, w.y, acc[3].y);
    acc[3].z = fmaf(xa.w, w.z, acc[3].z); acc[3].w = fmaf(xa.w, w.w, acc[3].w);
    acc[4].x = fmaf(xb.x, w.x, acc[4].x); acc[4].y = fmaf(xb.x, w.y, acc[4].y);
    acc[4].z = fmaf(xb.x, w.z, acc[4].z); acc[4].w = fmaf(xb.x, w.w, acc[4].w);
    acc[5].x = fmaf(xb.y, w.x, acc[5].x); acc[5].y = fmaf(xb.y, w.y, acc[5].y);
    acc[5].z = fmaf(xb.y, w.z, acc[5].z); acc[5].w = fmaf(xb.y, w.w, acc[5].w);
    acc[6].x = fmaf(xb.z, w.x, acc[6].x); acc[6].y = fmaf(xb.z, w.y, acc[6].y);
    acc[6].z = fmaf(xb.z, w.z, acc[6].z); acc[6].w = fmaf(xb.z, w.w, acc[6].w);
    acc[7].x = fmaf(xb.w, w.x, acc[7].x); acc[7].y = fmaf(xb.w, w.y, acc[7].y);
    acc[7].z = fmaf(xb.w, w.z, acc[7].z); acc[7].w = fmaf(xb.w, w.w, acc[7].w);
  }
  float4 av = ((const float4*)atts)[m];
  float4 dv = ((const float4*)attd)[m];
  int h = m >> 3;
  #pragma unroll
  for (int rr = 0; rr < 8; ++rr){
    int n = n0 + rowbase + rr;
    if (n < N){
      union { __half2 hh[2]; float2 f; } u;
      u.hh[0] = __floats2half2_rn(acc[rr].x, acc[rr].y);
      u.hh[1] = __floats2half2_rn(acc[rr].z, acc[rr].w);
      ((float2*)(h1 + (size_t)n * 128))[m] = u.f;
    }
    float s  = acc[rr].x * av.x + acc[rr].y * av.y + acc[rr].z * av.z + acc[rr].w * av.w;
    float dd = acc[rr].x * dv.x + acc[rr].y * dv.y + acc[rr].z * dv.z + acc[rr].w * dv.w;
    #pragma unroll
    for (int off = 4; off; off >>= 1){
      s  += __shfl_down(s, off);
      dd += __shfl_down(dd, off);
    }
    if ((m & 7) == 0 && n < N){
      as1[n * 4 + h] = s;
      ad1[n * 4 + h] = dd;
    }
  }
}

// global per-head max of a_s (upper bound for layer-1 softmax stabilization)
__global__ void k_asmax(const float* __restrict__ as1, unsigned* __restrict__ asmaxu, int N4){
  float mx = -INFINITY;
  for (int i = blockIdx.x * blockDim.x + threadIdx.x; i < N4; i += gridDim.x * blockDim.x)
    mx = fmaxf(mx, as1[i]);
  #pragma unroll
  for (int off = 4; off < 64; off <<= 1) mx = fmaxf(mx, __shfl_xor(mx, off));
  if ((threadIdx.x & 63) < 4) atomicMax(&asmaxu[(threadIdx.x & 3)], fenc(mx));
}

// ---- CSR build: 2-level counting sort, LDS atomics only ----

// Pass A: per-block bucket histogram
__global__ void k_bhist(const int* __restrict__ ei, int* __restrict__ gcnt,
                        int E, int N, int B, int chunk){
  __shared__ int hist[512];
  for (int t = threadIdx.x; t < B; t += 256) hist[t] = 0;
  __syncthreads();
  int T = E + N;
  int lo = blockIdx.x * chunk;
  int hi = min(lo + chunk, T);
  for (int i = lo + (int)threadIdx.x; i < hi; i += 256){
    int d = (i < E) ? ei[E + i] : (i - E);
    atomicAdd(&hist[d >> BSHIFT], 1);
  }
  __syncthreads();
  for (int t = threadIdx.x; t < B; t += 256) gcnt[blockIdx.x * B + t] = hist[t];
}

// Pass B1: one block per bucket — scan its 256 per-block counts.
__global__ void k_bprefix(const int* __restrict__ gcnt, int* __restrict__ ecur,
                          int* __restrict__ btot, int B){
  int b = blockIdx.x;
  int t = threadIdx.x;            // = source block id
  int v = gcnt[t * B + b];
  int lane = t & 63, wid = t >> 6;
  int x = v;
  #pragma unroll
  for (int off = 1; off < 64; off <<= 1){
    int tmp = __shfl_up(x, off, 64);
    if (lane >= off) x += tmp;
  }
  __shared__ int ws[4];
  if (lane == 63) ws[wid] = x;
  __syncthreads();
  if (t == 0){
    int s = 0;
    #pragma unroll
    for (int i = 0; i < 4; ++i){ int tmp = ws[i]; ws[i] = s; s += tmp; }
  }
  __syncthreads();
  int excl = ws[wid] + x - v;
  ecur[b * NB + t] = excl;
  if (t == 255) btot[b] = excl + v;
}

// Pass B2: single block — exclusive scan of the B bucket totals -> bstart.
__global__ void k_btscan(const int* __restrict__ btot, int* __restrict__ bstart,
                         int B, int T){
  __shared__ int wsum[16];
  __shared__ int carry_s;
  int lane = threadIdx.x & 63, wid = threadIdx.x >> 6;
  if (threadIdx.x == 0) carry_s = 0;
  __syncthreads();
  for (int base = 0; base < B; base += 1024){
    int i = base + (int)threadIdx.x;
    int v = (i < B) ? btot[i] : 0;
    int x = v;
    #pragma unroll
    for (int off = 1; off < 64; off <<= 1){
      int t = __shfl_up(x, off, 64);
      if (lane >= off) x += t;
    }
    if (lane == 63) wsum[wid] = x;
    __syncthreads();
    if (wid == 0 && lane < 16){
      int w = wsum[lane];
      #pragma unroll
      for (int off = 1; off < 16; off <<= 1){
        int t = __shfl_up(w, off, 64);
        if (lane >= off) w += t;
      }
      wsum[lane] = w;
    }
    __syncthreads();
    int carry = carry_s;
    int prefix = carry + (wid ? wsum[wid - 1] : 0);
    if (i < B) bstart[i] = prefix + x - v;
    __syncthreads();
    if (threadIdx.x == 1023) carry_s = carry + wsum[15];
    __syncthreads();
  }
  if (threadIdx.x == 0) bstart[B] = T;
}

// Pass C: scatter (src,dst) pairs into bucket-partitioned ebuf
__global__ void k_bscatter(const int* __restrict__ ei, const int* __restrict__ ecur,
                           const int* __restrict__ bstart,
                           unsigned long long* __restrict__ ebuf,
                           int E, int N, int B, int chunk){
  __shared__ int cur[512];
  for (int t = threadIdx.x; t < B; t += 256)
    cur[t] = ecur[t * NB + blockIdx.x] + bstart[t];
  __syncthreads();
  int T = E + N;
  int lo = blockIdx.x * chunk;
  int hi = min(lo + chunk, T);
  for (int i = lo + (int)threadIdx.x; i < hi; i += 256){
    int s, d;
    if (i < E){ s = ei[i]; d = ei[E + i]; } else { s = d = i - E; }
    int pos = atomicAdd(&cur[d >> BSHIFT], 1);
    ebuf[pos] = ((unsigned long long)(unsigned)d << 32) | (unsigned)s;
  }
}

// Pass D: one block per bucket; LDS 128-dst hist + scan -> rs + final csr
__global__ void k_bfinal(const unsigned long long* __restrict__ ebuf,
                         const int* __restrict__ bstart,
                         int* __restrict__ csr, int* __restrict__ rs,
                         int N, int B, int T){
  int b = blockIdx.x;
  int d0 = b << BSHIFT;
  int dcount = min(128, N - d0);
  int ebeg = bstart[b];
  int eend = bstart[b + 1];
  __shared__ int hist[128];
  __shared__ int excl[128];
  if (threadIdx.x < 128) hist[threadIdx.x] = 0;
  __syncthreads();
  for (int i = ebeg + (int)threadIdx.x; i < eend; i += 256)
    atomicAdd(&hist[(int)(ebuf[i] >> 32) - d0], 1);
  __syncthreads();
  if (threadIdx.x < 64){
    int l = threadIdx.x;
    int v0 = hist[l], v1 = hist[l + 64];
    int s0 = v0, s1 = v1;
    #pragma unroll
    for (int off = 1; off < 64; off <<= 1){
      int t0 = __shfl_up(s0, off, 64); if (l >= off) s0 += t0;
      int t1 = __shfl_up(s1, off, 64); if (l >= off) s1 += t1;
    }
    int tot0 = __shfl(s0, 63, 64);
    excl[l] = s0 - v0;
    excl[l + 64] = tot0 + s1 - v1;
  }
  __syncthreads();
  if (threadIdx.x < dcount) rs[d0 + threadIdx.x] = ebeg + excl[threadIdx.x];
  if (threadIdx.x < 128) hist[threadIdx.x] = excl[threadIdx.x];  // -> cursor
  if (b == 0 && threadIdx.x == 255) rs[N] = T;
  __syncthreads();
  for (int i = ebeg + (int)threadIdx.x; i < eend; i += 256){
    unsigned long long e = ebuf[i];
    int d = (int)(e >> 32);
    int pos = ebeg + atomicAdd(&hist[d - d0], 1);
    csr[pos] = (int)(e & 0xFFFFFFFFu);
  }
}

// ---- Layer 1 aggregation: one wave per dst, 16 lanes per edge (8 fp16 ch/lane),
// 4 edges in flight. Softmax via global upper bound (no max pass). Fuses
// /den, +bias, ELU, dot W2 -> h2[d]. Zero atomics.
__global__ void k_agg1(const int* __restrict__ csr, const int* __restrict__ rs,
                       const float* __restrict__ as1, const float* __restrict__ ad1,
                       const unsigned* __restrict__ asmaxu,
                       const float4* __restrict__ h1,
                       const float* __restrict__ bias1,
                       const float* __restrict__ W2, float* __restrict__ h2, int N){
  int wv = threadIdx.x >> 6;
  int lane = threadIdx.x & 63;
  int d = blockIdx.x * 4 + wv;
  if (d >= N) return;
  int g = lane >> 4;          // edge subgroup 0..3
  int m = lane & 15;          // channels 8m..8m+7
  int h = m >> 2;             // head
  float adh = ad1[d * 4 + h];
  float M = lrelu(fdec(asmaxu[h]) + adh);
  int beg = rs[d], end = rs[d + 1];
  float den = 0.f;
  float a0=0.f,a1=0.f,a2=0.f,a3=0.f,a4=0.f,a5=0.f,a6=0.f,a7=0.f;
  for (int j = beg; j < end; j += 4){
    int slot = j + g;
    bool v = slot < end;
    int s = csr[v ? slot : beg];
    float e = lrelu(as1[s * 4 + h] + adh);
    float p = v ? __expf(e - M) : 0.f;
    float4 raw = h1[(size_t)s * 16 + m];
    float2 c01 = __half22float2(*(__half2*)&raw.x);
    float2 c23 = __half22float2(*(__half2*)&raw.y);
    float2 c45 = __half22float2(*(__half2*)&raw.z);
    float2 c67 = __half22float2(*(__half2*)&raw.w);
    den += p;
    a0 = fmaf(p, c01.x, a0); a1 = fmaf(p, c01.y, a1);
    a2 = fmaf(p, c23.x, a2); a3 = fmaf(p, c23.y, a3);
    a4 = fmaf(p, c45.x, a4); a5 = fmaf(p, c45.y, a5);
    a6 = fmaf(p, c67.x, a6); a7 = fmaf(p, c67.y, a7);
  }
  #define CMB(v) v += __shfl_xor(v, 16); v += __shfl_xor(v, 32);
  CMB(a0) CMB(a1) CMB(a2) CMB(a3) CMB(a4) CMB(a5) CMB(a6) CMB(a7) CMB(den)
  #undef CMB
  float part = 0.f;
  if (lane < 16){
    float invden = 1.f / den;
    float4 b03 = ((const float4*)bias1)[2 * m];
    float4 b47 = ((const float4*)bias1)[2 * m + 1];
    float4 w03 = ((const float4*)W2)[2 * m];
    float4 w47 = ((const float4*)W2)[2 * m + 1];
    part  = elu1(a0 * invden + b03.x) * w03.x;
    part += elu1(a1 * invden + b03.y) * w03.y;
    part += elu1(a2 * invden + b03.z) * w03.z;
    part += elu1(a3 * invden + b03.w) * w03.w;
    part += elu1(a4 * invden + b47.x) * w47.x;
    part += elu1(a5 * invden + b47.y) * w47.y;
    part += elu1(a6 * invden + b47.z) * w47.z;
    part += elu1(a7 * invden + b47.w) * w47.w;
  }
  #pragma unroll
  for (int off = 8; off; off >>= 1) part += __shfl_down(part, off);
  if (lane == 0) h2[d] = part;
}

// global min/max of h2 (upper bound inputs for layer-2 softmax)
__global__ void k_h2mm(const float* __restrict__ h2, unsigned* __restrict__ h2mm, int N){
  float mx = -INFINITY, mn = INFINITY;
  for (int i = blockIdx.x * blockDim.x + threadIdx.x; i < N; i += gridDim.x * blockDim.x){
    float v = h2[i];
    mx = fmaxf(mx, v); mn = fminf(mn, v);
  }
  #pragma unroll
  for (int off = 1; off < 64; off <<= 1){
    mx = fmaxf(mx, __shfl_xor(mx, off));
    mn = fminf(mn, __shfl_xor(mn, off));
  }
  if ((threadIdx.x & 63) == 0){
    atomicMax(&h2mm[0], fenc(mx));
    atomicMax(&h2mm[1], fenc(-mn));
  }
}

// Layer 2: one wave per dst, single pass (bound-stabilized softmax).
__global__ void k_agg2(const int* __restrict__ csr, const int* __restrict__ rs,
                       const float* __restrict__ h2, const unsigned* __restrict__ h2mm,
                       const float* __restrict__ as2p, const float* __restrict__ ad2p,
                       const float* __restrict__ bias2, float* __restrict__ out, int N){
  int wv = threadIdx.x >> 6;
  int lane = threadIdx.x & 63;
  int d = blockIdx.x * 4 + wv;
  if (d >= N) return;
  float asc = as2p[0];
  float hmax = fdec(h2mm[0]), hmn = -fdec(h2mm[1]);
  float bound = (asc >= 0.f) ? asc * hmax : asc * hmn;
  float hd = h2[d] * ad2p[0];
  float M = lrelu(bound + hd);
  int beg = rs[d], end = rs[d + 1];
  float den = 0.f, acc = 0.f;
  for (int j = beg + lane; j < end; j += 64){
    float hs = h2[csr[j]];
    float p = __expf(lrelu(hs * asc + hd) - M);
    den += p;
    acc = fmaf(p, hs, acc);
  }
  #pragma unroll
  for (int off = 32; off; off >>= 1){
    den += __shfl_xor(den, off);
    acc += __shfl_xor(acc, off);
  }
  if (lane == 0) out[d] = acc / den + bias2[0];
}

extern "C" void kernel_launch(void* const* d_in, const int* in_sizes, int n_in,
                              void* d_out, int out_size, void* d_ws, size_t ws_size,
                              hipStream_t stream){
  const float* x     = (const float*)d_in[0];
  const int*   ei    = (const int*)  d_in[1];
  const float* W1    = (const float*)d_in[2];
  const float* atts1 = (const float*)d_in[3];
  const float* attd1 = (const float*)d_in[4];
  const float* bias1 = (const float*)d_in[5];
  const float* W2    = (const float*)d_in[6];
  const float* atts2 = (const float*)d_in[7];
  const float* attd2 = (const float*)d_in[8];
  const float* bias2 = (const float*)d_in[9];

  int N = in_sizes[0] / 128;   // D = 128
  int E = in_sizes[1] / 2;
  int T = E + N;
  int B = (N + 127) >> BSHIFT;           // dst buckets of 128
  int chunk = (T + NB - 1) / NB;

  // workspace layout (bytes)
  char* p = (char*)d_ws;
  unsigned long long* ebuf = (unsigned long long*)p; p += (size_t)T * 8;
  __half* h1   = (__half*)p;  p += (size_t)N * 128 * 2;
  float*  as1  = (float*)p;   p += (size_t)N * 4 * 4;
  float*  ad1  = (float*)p;   p += (size_t)N * 4 * 4;
  float*  h2   = (float*)p;   p += (size_t)N * 4;
  int*    gcnt = (int*)p;     p += (size_t)NB * B * 4;
  int*    ecur = (int*)p;     p += (size_t)NB * B * 4;
  int*    csr  = (int*)p;     p += (size_t)T * 4;
  int*    rs   = (int*)p;     p += (size_t)(N + 1) * 4;
  int*    btot = (int*)p;     p += (size_t)B * 4;
  int*    bstart = (int*)p;   p += (size_t)(B + 1) * 4;
  unsigned* asmaxu = (unsigned*)p; p += 4 * 4;
  unsigned* h2mm   = (unsigned*)p;

  k_init    <<<1, 64, 0, stream>>>(asmaxu, h2mm);
  k_gemm1   <<<(N + 63) / 64, 256, 0, stream>>>(x, W1, atts1, attd1, h1, as1, ad1, N);
  k_asmax   <<<64, 256, 0, stream>>>(as1, asmaxu, N * 4);
  k_bhist   <<<NB, 256, 0, stream>>>(ei, gcnt, E, N, B, chunk);
  k_bprefix <<<B, 256, 0, stream>>>(gcnt, ecur, btot, B);
  k_btscan  <<<1, 1024, 0, stream>>>(btot, bstart, B, T);
  k_bscatter<<<NB, 256, 0, stream>>>(ei, ecur, bstart, ebuf, E, N, B, chunk);
  k_bfinal  <<<B, 256, 0, stream>>>(ebuf, bstart, csr, rs, N, B, T);
  k_agg1    <<<(N + 3) / 4, 256, 0, stream>>>(csr, rs, as1, ad1, asmaxu,
                                              (const float4*)h1, bias1, W2, h2, N);
  k_h2mm    <<<64, 256, 0, stream>>>(h2, h2mm, N);
  k_agg2    <<<(N + 3) / 4, 256, 0, stream>>>(csr, rs, h2, h2mm, atts2, attd2,
                                              bias2, (float*)d_out, N);
}

// Round 8
// 176.430 us; speedup vs baseline: 8.5973x; 1.0630x over previous
//
#include <hip/hip_runtime.h>
#include <hip/hip_fp16.h>

#define NEG_SLOPE 0.2f
#define BSHIFT 7          // bucket = dst >> 7  (128 dsts per bucket)
#define NB 256            // blocks in bucket hist/scatter passes

__device__ __forceinline__ float lrelu(float x){ return x > 0.f ? x : NEG_SLOPE * x; }
__device__ __forceinline__ float elu1(float x){ return x > 0.f ? x : expm1f(x); }
// float -> ordered uint encoding for atomicMax over signed floats
__device__ __forceinline__ unsigned fenc(float f){
  unsigned u = __float_as_uint(f);
  return (u & 0x80000000u) ? ~u : (u | 0x80000000u);
}
__device__ __forceinline__ float fdec(unsigned u){
  return (u & 0x80000000u) ? __uint_as_float(u & 0x7fffffffu) : __uint_as_float(~u);
}

__global__ void k_init(unsigned* asmaxu, unsigned* h2mm){
  int i = threadIdx.x;
  if (i < 4) asmaxu[i] = 0u;
  if (i < 2) h2mm[i] = 0u;
}

// h1 = x @ W1 (fp16 out), fused a_s/a_d row dots (fp32).
// 128 rows x 128 cols per block, 256 threads, 8x8 register tile per thread.
// x staged TRANSPOSED in LDS xs[k][row], 128x128 fp32 = 64 KB exactly.
//  - LDS writes: lane-distinct rows -> bank=row%32, 2-way (free).
//  - LDS reads: 4 distinct b128 addrs/wave at 32-float stride -> banks
//    {0,8,16,24}, broadcast to 16 lanes, conflict-free.
__global__ __launch_bounds__(256) void k_gemm1(
    const float* __restrict__ x, const float* __restrict__ W1,
    const float* __restrict__ atts, const float* __restrict__ attd,
    __half* __restrict__ h1, float* __restrict__ as1, float* __restrict__ ad1,
    int N){
  __shared__ float xs[128 * 128];   // [k][row], 64 KB
  int n0 = blockIdx.x * 128;
  int t = threadIdx.x;
  {
    int row = t & 127;
    int kc = t >> 7;                // 0 or 1 (k-half)
    int n = n0 + row;
    const float4* x4 = (const float4*)x;
    #pragma unroll 4
    for (int i = 0; i < 16; ++i){
      float4 v = (n < N) ? x4[(size_t)n * 32 + kc * 16 + i]
                         : make_float4(0.f, 0.f, 0.f, 0.f);
      int k = kc * 64 + 4 * i;
      xs[(k + 0) * 128 + row] = v.x;
      xs[(k + 1) * 128 + row] = v.y;
      xs[(k + 2) * 128 + row] = v.z;
      xs[(k + 3) * 128 + row] = v.w;
    }
  }
  __syncthreads();
  int m = t & 15;                 // cols 8m..8m+7
  int rg = t >> 4;                // rows 8rg..8rg+7
  int rb = rg * 8;
  const float4* W14 = (const float4*)W1;
  float acc[8][8];
  #pragma unroll
  for (int r = 0; r < 8; ++r)
    #pragma unroll
    for (int c = 0; c < 8; ++c) acc[r][c] = 0.f;
  #pragma unroll 2
  for (int k = 0; k < 128; ++k){
    float4 w0 = W14[k * 32 + 2 * m];
    float4 w1 = W14[k * 32 + 2 * m + 1];
    float4 xa = *(const float4*)&xs[k * 128 + rb];
    float4 xb = *(const float4*)&xs[k * 128 + rb + 4];
    float xr[8] = {xa.x, xa.y, xa.z, xa.w, xb.x, xb.y, xb.z, xb.w};
    float wc[8] = {w0.x, w0.y, w0.z, w0.w, w1.x, w1.y, w1.z, w1.w};
    #pragma unroll
    for (int r = 0; r < 8; ++r)
      #pragma unroll
      for (int c = 0; c < 8; ++c)
        acc[r][c] = fmaf(xr[r], wc[c], acc[r][c]);
  }
  float4 av0 = ((const float4*)atts)[2 * m], av1 = ((const float4*)atts)[2 * m + 1];
  float4 dv0 = ((const float4*)attd)[2 * m], dv1 = ((const float4*)attd)[2 * m + 1];
  int h = m >> 2;                 // head of cols 8m..8m+7
  #pragma unroll
  for (int r = 0; r < 8; ++r){
    int n = n0 + rb + r;
    if (n < N){
      union { __half2 hh[4]; float4 f; } u;
      u.hh[0] = __floats2half2_rn(acc[r][0], acc[r][1]);
      u.hh[1] = __floats2half2_rn(acc[r][2], acc[r][3]);
      u.hh[2] = __floats2half2_rn(acc[r][4], acc[r][5]);
      u.hh[3] = __floats2half2_rn(acc[r][6], acc[r][7]);
      *(float4*)(h1 + (size_t)n * 128 + 8 * m) = u.f;
    }
    float s  = acc[r][0]*av0.x + acc[r][1]*av0.y + acc[r][2]*av0.z + acc[r][3]*av0.w
             + acc[r][4]*av1.x + acc[r][5]*av1.y + acc[r][6]*av1.z + acc[r][7]*av1.w;
    float dd = acc[r][0]*dv0.x + acc[r][1]*dv0.y + acc[r][2]*dv0.z + acc[r][3]*dv0.w
             + acc[r][4]*dv1.x + acc[r][5]*dv1.y + acc[r][6]*dv1.z + acc[r][7]*dv1.w;
    s  += __shfl_down(s, 1);  s  += __shfl_down(s, 2);
    dd += __shfl_down(dd, 1); dd += __shfl_down(dd, 2);
    if ((m & 3) == 0 && n < N){
      as1[n * 4 + h] = s;
      ad1[n * 4 + h] = dd;
    }
  }
}

// global per-head max of a_s (upper bound for layer-1 softmax stabilization)
__global__ void k_asmax(const float* __restrict__ as1, unsigned* __restrict__ asmaxu, int N4){
  float mx = -INFINITY;
  for (int i = blockIdx.x * blockDim.x + threadIdx.x; i < N4; i += gridDim.x * blockDim.x)
    mx = fmaxf(mx, as1[i]);
  #pragma unroll
  for (int off = 4; off < 64; off <<= 1) mx = fmaxf(mx, __shfl_xor(mx, off));
  if ((threadIdx.x & 63) < 4) atomicMax(&asmaxu[(threadIdx.x & 3)], fenc(mx));
}

// ---- CSR build: 2-level counting sort, LDS atomics only ----

// Pass A: per-block bucket histogram
__global__ void k_bhist(const int* __restrict__ ei, int* __restrict__ gcnt,
                        int E, int N, int B, int chunk){
  __shared__ int hist[512];
  for (int t = threadIdx.x; t < B; t += 256) hist[t] = 0;
  __syncthreads();
  int T = E + N;
  int lo = blockIdx.x * chunk;
  int hi = min(lo + chunk, T);
  for (int i = lo + (int)threadIdx.x; i < hi; i += 256){
    int d = (i < E) ? ei[E + i] : (i - E);
    atomicAdd(&hist[d >> BSHIFT], 1);
  }
  __syncthreads();
  for (int t = threadIdx.x; t < B; t += 256) gcnt[blockIdx.x * B + t] = hist[t];
}

// Pass B1: one block per bucket — scan its 256 per-block counts.
__global__ void k_bprefix(const int* __restrict__ gcnt, int* __restrict__ ecur,
                          int* __restrict__ btot, int B){
  int b = blockIdx.x;
  int t = threadIdx.x;            // = source block id
  int v = gcnt[t * B + b];
  int lane = t & 63, wid = t >> 6;
  int x = v;
  #pragma unroll
  for (int off = 1; off < 64; off <<= 1){
    int tmp = __shfl_up(x, off, 64);
    if (lane >= off) x += tmp;
  }
  __shared__ int ws[4];
  if (lane == 63) ws[wid] = x;
  __syncthreads();
  if (t == 0){
    int s = 0;
    #pragma unroll
    for (int i = 0; i < 4; ++i){ int tmp = ws[i]; ws[i] = s; s += tmp; }
  }
  __syncthreads();
  int excl = ws[wid] + x - v;
  ecur[b * NB + t] = excl;
  if (t == 255) btot[b] = excl + v;
}

// Pass B2: single block — exclusive scan of the B bucket totals -> bstart.
__global__ void k_btscan(const int* __restrict__ btot, int* __restrict__ bstart,
                         int B, int T){
  __shared__ int wsum[16];
  __shared__ int carry_s;
  int lane = threadIdx.x & 63, wid = threadIdx.x >> 6;
  if (threadIdx.x == 0) carry_s = 0;
  __syncthreads();
  for (int base = 0; base < B; base += 1024){
    int i = base + (int)threadIdx.x;
    int v = (i < B) ? btot[i] : 0;
    int x = v;
    #pragma unroll
    for (int off = 1; off < 64; off <<= 1){
      int t = __shfl_up(x, off, 64);
      if (lane >= off) x += t;
    }
    if (lane == 63) wsum[wid] = x;
    __syncthreads();
    if (wid == 0 && lane < 16){
      int w = wsum[lane];
      #pragma unroll
      for (int off = 1; off < 16; off <<= 1){
        int t = __shfl_up(w, off, 64);
        if (lane >= off) w += t;
      }
      wsum[lane] = w;
    }
    __syncthreads();
    int carry = carry_s;
    int prefix = carry + (wid ? wsum[wid - 1] : 0);
    if (i < B) bstart[i] = prefix + x - v;
    __syncthreads();
    if (threadIdx.x == 1023) carry_s = carry + wsum[15];
    __syncthreads();
  }
  if (threadIdx.x == 0) bstart[B] = T;
}

// Pass C: scatter (src,dst) pairs into bucket-partitioned ebuf
__global__ void k_bscatter(const int* __restrict__ ei, const int* __restrict__ ecur,
                           const int* __restrict__ bstart,
                           unsigned long long* __restrict__ ebuf,
                           int E, int N, int B, int chunk){
  __shared__ int cur[512];
  for (int t = threadIdx.x; t < B; t += 256)
    cur[t] = ecur[t * NB + blockIdx.x] + bstart[t];
  __syncthreads();
  int T = E + N;
  int lo = blockIdx.x * chunk;
  int hi = min(lo + chunk, T);
  for (int i = lo + (int)threadIdx.x; i < hi; i += 256){
    int s, d;
    if (i < E){ s = ei[i]; d = ei[E + i]; } else { s = d = i - E; }
    int pos = atomicAdd(&cur[d >> BSHIFT], 1);
    ebuf[pos] = ((unsigned long long)(unsigned)d << 32) | (unsigned)s;
  }
}

// Pass D: one block per bucket; LDS 128-dst hist + scan -> rs + final csr
__global__ void k_bfinal(const unsigned long long* __restrict__ ebuf,
                         const int* __restrict__ bstart,
                         int* __restrict__ csr, int* __restrict__ rs,
                         int N, int B, int T){
  int b = blockIdx.x;
  int d0 = b << BSHIFT;
  int dcount = min(128, N - d0);
  int ebeg = bstart[b];
  int eend = bstart[b + 1];
  __shared__ int hist[128];
  __shared__ int excl[128];
  if (threadIdx.x < 128) hist[threadIdx.x] = 0;
  __syncthreads();
  for (int i = ebeg + (int)threadIdx.x; i < eend; i += 256)
    atomicAdd(&hist[(int)(ebuf[i] >> 32) - d0], 1);
  __syncthreads();
  if (threadIdx.x < 64){
    int l = threadIdx.x;
    int v0 = hist[l], v1 = hist[l + 64];
    int s0 = v0, s1 = v1;
    #pragma unroll
    for (int off = 1; off < 64; off <<= 1){
      int t0 = __shfl_up(s0, off, 64); if (l >= off) s0 += t0;
      int t1 = __shfl_up(s1, off, 64); if (l >= off) s1 += t1;
    }
    int tot0 = __shfl(s0, 63, 64);
    excl[l] = s0 - v0;
    excl[l + 64] = tot0 + s1 - v1;
  }
  __syncthreads();
  if (threadIdx.x < dcount) rs[d0 + threadIdx.x] = ebeg + excl[threadIdx.x];
  if (threadIdx.x < 128) hist[threadIdx.x] = excl[threadIdx.x];  // -> cursor
  if (b == 0 && threadIdx.x == 255) rs[N] = T;
  __syncthreads();
  for (int i = ebeg + (int)threadIdx.x; i < eend; i += 256){
    unsigned long long e = ebuf[i];
    int d = (int)(e >> 32);
    int pos = ebeg + atomicAdd(&hist[d - d0], 1);
    csr[pos] = (int)(e & 0xFFFFFFFFu);
  }
}

// ---- Layer 1 aggregation: one wave per dst, 16 lanes per edge (8 fp16 ch/lane),
// 8 edges in flight (2 independent chains of 4). Softmax via global upper bound.
// Fuses /den, +bias, ELU, dot W2 -> h2[d]. Zero atomics.
__global__ void k_agg1(const int* __restrict__ csr, const int* __restrict__ rs,
                       const float* __restrict__ as1, const float* __restrict__ ad1,
                       const unsigned* __restrict__ asmaxu,
                       const float4* __restrict__ h1,
                       const float* __restrict__ bias1,
                       const float* __restrict__ W2, float* __restrict__ h2, int N){
  int wv = threadIdx.x >> 6;
  int lane = threadIdx.x & 63;
  int d = blockIdx.x * 4 + wv;
  if (d >= N) return;
  int g = lane >> 4;          // edge subgroup 0..3
  int m = lane & 15;          // channels 8m..8m+7
  int h = m >> 2;             // head
  float adh = ad1[d * 4 + h];
  float M = lrelu(fdec(asmaxu[h]) + adh);
  int beg = rs[d], end = rs[d + 1];
  float den = 0.f;
  float a0=0.f,a1=0.f,a2=0.f,a3=0.f,a4=0.f,a5=0.f,a6=0.f,a7=0.f;
  int j = beg;
  for (; j + 8 <= end; j += 8){
    int sA = csr[j + g];
    int sB = csr[j + 4 + g];
    float eA = lrelu(as1[sA * 4 + h] + adh);
    float eB = lrelu(as1[sB * 4 + h] + adh);
    float pA = __expf(eA - M);
    float pB = __expf(eB - M);
    float4 rA = h1[(size_t)sA * 16 + m];
    float4 rB = h1[(size_t)sB * 16 + m];
    den += pA + pB;
    float2 cA0 = __half22float2(*(__half2*)&rA.x);
    float2 cA1 = __half22float2(*(__half2*)&rA.y);
    float2 cA2 = __half22float2(*(__half2*)&rA.z);
    float2 cA3 = __half22float2(*(__half2*)&rA.w);
    a0 = fmaf(pA, cA0.x, a0); a1 = fmaf(pA, cA0.y, a1);
    a2 = fmaf(pA, cA1.x, a2); a3 = fmaf(pA, cA1.y, a3);
    a4 = fmaf(pA, cA2.x, a4); a5 = fmaf(pA, cA2.y, a5);
    a6 = fmaf(pA, cA3.x, a6); a7 = fmaf(pA, cA3.y, a7);
    float2 cB0 = __half22float2(*(__half2*)&rB.x);
    float2 cB1 = __half22float2(*(__half2*)&rB.y);
    float2 cB2 = __half22float2(*(__half2*)&rB.z);
    float2 cB3 = __half22float2(*(__half2*)&rB.w);
    a0 = fmaf(pB, cB0.x, a0); a1 = fmaf(pB, cB0.y, a1);
    a2 = fmaf(pB, cB1.x, a2); a3 = fmaf(pB, cB1.y, a3);
    a4 = fmaf(pB, cB2.x, a4); a5 = fmaf(pB, cB2.y, a5);
    a6 = fmaf(pB, cB3.x, a6); a7 = fmaf(pB, cB3.y, a7);
  }
  for (; j < end; j += 4){
    int slot = j + g;
    bool v = slot < end;
    int s = csr[v ? slot : beg];
    float e = lrelu(as1[s * 4 + h] + adh);
    float p = v ? __expf(e - M) : 0.f;
    float4 raw = h1[(size_t)s * 16 + m];
    float2 c01 = __half22float2(*(__half2*)&raw.x);
    float2 c23 = __half22float2(*(__half2*)&raw.y);
    float2 c45 = __half22float2(*(__half2*)&raw.z);
    float2 c67 = __half22float2(*(__half2*)&raw.w);
    den += p;
    a0 = fmaf(p, c01.x, a0); a1 = fmaf(p, c01.y, a1);
    a2 = fmaf(p, c23.x, a2); a3 = fmaf(p, c23.y, a3);
    a4 = fmaf(p, c45.x, a4); a5 = fmaf(p, c45.y, a5);
    a6 = fmaf(p, c67.x, a6); a7 = fmaf(p, c67.y, a7);
  }
  #define CMB(v) v += __shfl_xor(v, 16); v += __shfl_xor(v, 32);
  CMB(a0) CMB(a1) CMB(a2) CMB(a3) CMB(a4) CMB(a5) CMB(a6) CMB(a7) CMB(den)
  #undef CMB
  float part = 0.f;
  if (lane < 16){
    float invden = 1.f / den;
    float4 b03 = ((const float4*)bias1)[2 * m];
    float4 b47 = ((const float4*)bias1)[2 * m + 1];
    float4 w03 = ((const float4*)W2)[2 * m];
    float4 w47 = ((const float4*)W2)[2 * m + 1];
    part  = elu1(a0 * invden + b03.x) * w03.x;
    part += elu1(a1 * invden + b03.y) * w03.y;
    part += elu1(a2 * invden + b03.z) * w03.z;
    part += elu1(a3 * invden + b03.w) * w03.w;
    part += elu1(a4 * invden + b47.x) * w47.x;
    part += elu1(a5 * invden + b47.y) * w47.y;
    part += elu1(a6 * invden + b47.z) * w47.z;
    part += elu1(a7 * invden + b47.w) * w47.w;
  }
  #pragma unroll
  for (int off = 8; off; off >>= 1) part += __shfl_down(part, off);
  if (lane == 0) h2[d] = part;
}

// global min/max of h2 (upper bound inputs for layer-2 softmax)
__global__ void k_h2mm(const float* __restrict__ h2, unsigned* __restrict__ h2mm, int N){
  float mx = -INFINITY, mn = INFINITY;
  for (int i = blockIdx.x * blockDim.x + threadIdx.x; i < N; i += gridDim.x * blockDim.x){
    float v = h2[i];
    mx = fmaxf(mx, v); mn = fminf(mn, v);
  }
  #pragma unroll
  for (int off = 1; off < 64; off <<= 1){
    mx = fmaxf(mx, __shfl_xor(mx, off));
    mn = fminf(mn, __shfl_xor(mn, off));
  }
  if ((threadIdx.x & 63) == 0){
    atomicMax(&h2mm[0], fenc(mx));
    atomicMax(&h2mm[1], fenc(-mn));
  }
}

// Layer 2: one wave per dst, single pass (bound-stabilized softmax).
__global__ void k_agg2(const int* __restrict__ csr, const int* __restrict__ rs,
                       const float* __restrict__ h2, const unsigned* __restrict__ h2mm,
                       const float* __restrict__ as2p, const float* __restrict__ ad2p,
                       const float* __restrict__ bias2, float* __restrict__ out, int N){
  int wv = threadIdx.x >> 6;
  int lane = threadIdx.x & 63;
  int d = blockIdx.x * 4 + wv;
  if (d >= N) return;
  float asc = as2p[0];
  float hmax = fdec(h2mm[0]), hmn = -fdec(h2mm[1]);
  float bound = (asc >= 0.f) ? asc * hmax : asc * hmn;
  float hd = h2[d] * ad2p[0];
  float M = lrelu(bound + hd);
  int beg = rs[d], end = rs[d + 1];
  float den = 0.f, acc = 0.f;
  for (int j = beg + lane; j < end; j += 64){
    float hs = h2[csr[j]];
    float p = __expf(lrelu(hs * asc + hd) - M);
    den += p;
    acc = fmaf(p, hs, acc);
  }
  #pragma unroll
  for (int off = 32; off; off >>= 1){
    den += __shfl_xor(den, off);
    acc += __shfl_xor(acc, off);
  }
  if (lane == 0) out[d] = acc / den + bias2[0];
}

extern "C" void kernel_launch(void* const* d_in, const int* in_sizes, int n_in,
                              void* d_out, int out_size, void* d_ws, size_t ws_size,
                              hipStream_t stream){
  const float* x     = (const float*)d_in[0];
  const int*   ei    = (const int*)  d_in[1];
  const float* W1    = (const float*)d_in[2];
  const float* atts1 = (const float*)d_in[3];
  const float* attd1 = (const float*)d_in[4];
  const float* bias1 = (const float*)d_in[5];
  const float* W2    = (const float*)d_in[6];
  const float* atts2 = (const float*)d_in[7];
  const float* attd2 = (const float*)d_in[8];
  const float* bias2 = (const float*)d_in[9];

  int N = in_sizes[0] / 128;   // D = 128
  int E = in_sizes[1] / 2;
  int T = E + N;
  int B = (N + 127) >> BSHIFT;           // dst buckets of 128
  int chunk = (T + NB - 1) / NB;

  // workspace layout (bytes)
  char* p = (char*)d_ws;
  unsigned long long* ebuf = (unsigned long long*)p; p += (size_t)T * 8;
  __half* h1   = (__half*)p;  p += (size_t)N * 128 * 2;
  float*  as1  = (float*)p;   p += (size_t)N * 4 * 4;
  float*  ad1  = (float*)p;   p += (size_t)N * 4 * 4;
  float*  h2   = (float*)p;   p += (size_t)N * 4;
  int*    gcnt = (int*)p;     p += (size_t)NB * B * 4;
  int*    ecur = (int*)p;     p += (size_t)NB * B * 4;
  int*    csr  = (int*)p;     p += (size_t)T * 4;
  int*    rs   = (int*)p;     p += (size_t)(N + 1) * 4;
  int*    btot = (int*)p;     p += (size_t)B * 4;
  int*    bstart = (int*)p;   p += (size_t)(B + 1) * 4;
  unsigned* asmaxu = (unsigned*)p; p += 4 * 4;
  unsigned* h2mm   = (unsigned*)p;

  k_init    <<<1, 64, 0, stream>>>(asmaxu, h2mm);
  k_gemm1   <<<(N + 127) / 128, 256, 0, stream>>>(x, W1, atts1, attd1, h1, as1, ad1, N);
  k_asmax   <<<64, 256, 0, stream>>>(as1, asmaxu, N * 4);
  k_bhist   <<<NB, 256, 0, stream>>>(ei, gcnt, E, N, B, chunk);
  k_bprefix <<<B, 256, 0, stream>>>(gcnt, ecur, btot, B);
  k_btscan  <<<1, 1024, 0, stream>>>(btot, bstart, B, T);
  k_bscatter<<<NB, 256, 0, stream>>>(ei, ecur, bstart, ebuf, E, N, B, chunk);
  k_bfinal  <<<B, 256, 0, stream>>>(ebuf, bstart, csr, rs, N, B, T);
  k_agg1    <<<(N + 3) / 4, 256, 0, stream>>>(csr, rs, as1, ad1, asmaxu,
                                              (const float4*)h1, bias1, W2, h2, N);
  k_h2mm    <<<64, 256, 0, stream>>>(h2, h2mm, N);
  k_agg2    <<<(N + 3) / 4, 256, 0, stream>>>(csr, rs, h2, h2mm, atts2, attd2,
                                              bias2, (float*)d_out, N);
}